// Round 1
// baseline (9421.070 us; speedup 1.0000x reference)
//
#include <hip/hip_runtime.h>

#define DI __device__ __forceinline__

typedef __attribute__((ext_vector_type(4))) float f32x4;
typedef __attribute__((ext_vector_type(8))) short bf16x8;
typedef __attribute__((ext_vector_type(8))) unsigned short u16x8;

constexpr int Vv = 50257, NPAD = 50304, Ee = 512, Hh = 512, Bb = 16, TDn = 64, TEn = 256;

// ---- workspace layout (bytes, all 256-aligned) ----
constexpr size_t OFF_ENCP = 0;                                          // (B*TE, H) f32
constexpr size_t OFF_ENCT = OFF_ENCP + (size_t)Bb*TEn*Hh*4;             // (B, H, TE) f32
constexpr size_t OFF_G0E  = OFF_ENCT + (size_t)Bb*Hh*TEn*4;             // (TD*B, 4H) f32
constexpr size_t OFF_FCWB = OFF_G0E  + (size_t)TDn*Bb*4*Hh*4;           // (NPAD, H) bf16
constexpr size_t OFF_H1B  = OFF_FCWB + (size_t)NPAD*Hh*2;               // (TD*B, H) bf16
constexpr size_t OFF_Q    = OFF_H1B  + (size_t)TDn*Bb*Hh*2;             // (B, H) f32
constexpr size_t OFF_SC   = OFF_Q    + (size_t)Bb*Hh*4;                 // (B, TE) f32
constexpr size_t OFF_CTX  = OFF_SC   + (size_t)Bb*TEn*4;                // (B, H) f32
constexpr size_t OFF_H0   = OFF_CTX  + (size_t)Bb*Hh*4;                 // 2x (B,H)
constexpr size_t OFF_H1   = OFF_H0   + (size_t)2*Bb*Hh*4;               // 2x (B,H)
constexpr size_t OFF_C0   = OFF_H1   + (size_t)2*Bb*Hh*4;               // (B,H)
constexpr size_t OFF_C1   = OFF_C0   + (size_t)Bb*Hh*4;                 // (B,H)
constexpr size_t OFF_SYNC = OFF_C1   + (size_t)Bb*Hh*4;                 // 256 B

DI float dot4(f32x4 a, f32x4 b) { return a[0]*b[0] + a[1]*b[1] + a[2]*b[2] + a[3]*b[3]; }
DI float wsum(float v) { for (int m = 32; m; m >>= 1) v += __shfl_xor(v, m, 64); return v; }
DI float wmax(float v) { for (int m = 32; m; m >>= 1) v = fmaxf(v, __shfl_xor(v, m, 64)); return v; }
DI float tanhfast(float x) { float e = __expf(2.f * x); return 1.f - 2.f / (e + 1.f); }
DI float sigm(float x) { return 1.f / (1.f + __expf(-x)); }

DI unsigned short f2bf(float f) {
    unsigned u = __builtin_bit_cast(unsigned, f);
    unsigned r = (u + 0x7FFFu + ((u >> 16) & 1u)) >> 16;
    return (unsigned short)r;
}
DI u16x8 cvt8(f32x4 a, f32x4 b) {
    u16x8 r;
    r[0]=f2bf(a[0]); r[1]=f2bf(a[1]); r[2]=f2bf(a[2]); r[3]=f2bf(a[3]);
    r[4]=f2bf(b[0]); r[5]=f2bf(b[1]); r[6]=f2bf(b[2]); r[7]=f2bf(b[3]);
    return r;
}

// ---- grid barrier (generation-based; counters memset to 0 each launch) ----
DI void gsync(unsigned* cnt, unsigned* gen, unsigned nb) {
    __syncthreads();
    if (threadIdx.x == 0) {
        __threadfence();
        unsigned g = __hip_atomic_load(gen, __ATOMIC_RELAXED, __HIP_MEMORY_SCOPE_AGENT);
        if (atomicAdd(cnt, 1u) == nb - 1u) {
            __hip_atomic_store(cnt, 0u, __ATOMIC_RELAXED, __HIP_MEMORY_SCOPE_AGENT);
            __hip_atomic_store(gen, g + 1u, __ATOMIC_RELEASE, __HIP_MEMORY_SCOPE_AGENT);
        } else {
            while (__hip_atomic_load(gen, __ATOMIC_ACQUIRE, __HIP_MEMORY_SCOPE_AGENT) == g)
                __builtin_amdgcn_s_sleep(2);
        }
        __threadfence();
    }
    __syncthreads();
}

// ---- prep: fc_w f32 -> bf16, padded to NPAD rows ----
__global__ void prep_fcw_kernel(const float* __restrict__ src, unsigned short* __restrict__ dst) {
    size_t i = ((size_t)blockIdx.x * 256 + threadIdx.x) << 3;
    int n = (int)(i >> 9);
    u16x8 v = {0,0,0,0,0,0,0,0};
    if (n < Vv) {
        const float* p = src + i;
        v = cvt8(*(const f32x4*)p, *(const f32x4*)(p + 4));
    }
    *(u16x8*)(dst + i) = v;
}

// ---- prep: enc (B,TE,H) -> encT (B,H,TE) ----
__global__ void transpose_kernel(const float* __restrict__ enc, float* __restrict__ encT) {
    __shared__ float tile[32][33];
    const int b = blockIdx.z, e0 = blockIdx.x << 5, h0 = blockIdx.y << 5;
    const int tx = threadIdx.x, ty = threadIdx.y;  // 32 x 8
    #pragma unroll
    for (int i = 0; i < 4; ++i)
        tile[ty + i*8][tx] = enc[((size_t)(b*TEn + e0 + ty + i*8))*Hh + h0 + tx];
    __syncthreads();
    #pragma unroll
    for (int i = 0; i < 4; ++i)
        encT[((size_t)(b*Hh + h0 + ty + i*8))*TEn + e0 + tx] = tile[tx][ty + i*8];
}

// ---- MFMA bf16 GEMM: C[m][n] = sum_k A[m][k]*B[n][k] (+bias), 128x128x32 tiles ----
// SRCBF: A/B already bf16.  GATHER: A row via ids (embedding).  OUTM: 0 plain, 1 fc-scatter.
template<int SRCBF, int GATHER, int OUTM>
__global__ __launch_bounds__(256, 2) void gemm_bt(
    const void* __restrict__ Av, const void* __restrict__ Bv,
    const float* __restrict__ bias, const float* __restrict__ bias2,
    float* __restrict__ Cout, int M, int N, int K, int ldb,
    const int* __restrict__ ids, int NV)
{
    __shared__ unsigned short As[128*32], Bs[128*32];
    const int tid = threadIdx.x;
    const int bn = blockIdx.x, bm = blockIdx.y;
    const int w = tid >> 6, l = tid & 63;
    const int wm = w >> 1, wn = w & 1;
    const int lr = l & 15, ls = l >> 4;
    f32x4 acc[4][4] = {};

    const int r0 = tid >> 2, c0 = (tid & 3) << 3;

    for (int kb = 0; kb < K; kb += 32) {
        #pragma unroll
        for (int half = 0; half < 2; ++half) {
            const int rr = r0 + half*64;
            {   // A tile
                const int gm = bm*128 + rr;
                size_t arow = GATHER ? (size_t)ids[((gm & 15) << 6) + (gm >> 4)] : (size_t)gm;
                u16x8 v;
                if (SRCBF) {
                    v = *(const u16x8*)((const unsigned short*)Av + arow*(size_t)K + kb + c0);
                } else {
                    const float* ap = (const float*)Av + arow*(size_t)K + kb + c0;
                    v = cvt8(*(const f32x4*)ap, *(const f32x4*)(ap + 4));
                }
                *(u16x8*)&As[rr*32 + c0] = v;
            }
            {   // B tile
                const size_t brow = (size_t)(bn*128 + rr);
                u16x8 v;
                if (SRCBF) {
                    v = *(const u16x8*)((const unsigned short*)Bv + brow*(size_t)ldb + kb + c0);
                } else {
                    const float* bp = (const float*)Bv + brow*(size_t)ldb + kb + c0;
                    v = cvt8(*(const f32x4*)bp, *(const f32x4*)(bp + 4));
                }
                *(u16x8*)&Bs[rr*32 + c0] = v;
            }
        }
        __syncthreads();
        bf16x8 af[4], bfv[4];
        #pragma unroll
        for (int mt = 0; mt < 4; ++mt) af[mt]  = *(const bf16x8*)&As[(wm*64 + mt*16 + lr)*32 + ls*8];
        #pragma unroll
        for (int nt = 0; nt < 4; ++nt) bfv[nt] = *(const bf16x8*)&Bs[(wn*64 + nt*16 + lr)*32 + ls*8];
        #pragma unroll
        for (int mt = 0; mt < 4; ++mt)
            #pragma unroll
            for (int nt = 0; nt < 4; ++nt)
                acc[mt][nt] = __builtin_amdgcn_mfma_f32_16x16x32_bf16(af[mt], bfv[nt], acc[mt][nt], 0, 0, 0);
        __syncthreads();
    }

    #pragma unroll
    for (int mt = 0; mt < 4; ++mt) {
        #pragma unroll
        for (int nt = 0; nt < 4; ++nt) {
            const int n = bn*128 + wn*64 + nt*16 + lr;
            const int mbase = bm*128 + wm*64 + mt*16 + ls*4;
            f32x4 a = acc[mt][nt];
            #pragma unroll
            for (int r = 0; r < 4; ++r) {
                const int m = mbase + r;
                if (OUTM == 0) {
                    float v = a[r] + bias[n] + (bias2 ? bias2[n] : 0.f);
                    Cout[(size_t)m*N + n] = v;
                } else {
                    if (n < NV) {
                        float v = a[r] + bias[n];
                        Cout[(size_t)(((m & 15) << 6) + (m >> 4))*NV + n] = v;
                    }
                }
            }
        }
    }
}

// ---- cooperative recurrence: 64 steps, 5 barriers/step ----
__global__ __launch_bounds__(256, 2) void recur_kernel(
    const float* __restrict__ ih, const float* __restrict__ ic,
    const float* __restrict__ W2w, const float* __restrict__ W2b,
    const float* __restrict__ vw, const float* __restrict__ vb,
    const int* __restrict__ smask,
    const float* __restrict__ Wi0, const float* __restrict__ Wh0,
    const float* __restrict__ Wi1, const float* __restrict__ Wh1,
    const float* __restrict__ bi1, const float* __restrict__ bh1,
    char* __restrict__ ws)
{
    float* encP = (float*)(ws + OFF_ENCP);
    float* encT = (float*)(ws + OFF_ENCT);
    float* g0e  = (float*)(ws + OFF_G0E);
    unsigned short* h1bf = (unsigned short*)(ws + OFF_H1B);
    float* qb  = (float*)(ws + OFF_Q);
    float* sc  = (float*)(ws + OFF_SC);
    float* ctx = (float*)(ws + OFF_CTX);
    float* h0b = (float*)(ws + OFF_H0);
    float* h1v = (float*)(ws + OFF_H1);
    float* c0b = (float*)(ws + OFF_C0);
    float* c1b = (float*)(ws + OFF_C1);
    unsigned* cnt = (unsigned*)(ws + OFF_SYNC);
    unsigned* gen = cnt + 32;

    const int tid = threadIdx.x, bid = blockIdx.x;
    const int W = (bid << 2) + (tid >> 6), l = tid & 63;
    const unsigned NB = gridDim.x;
    const int k0 = l << 3;

    // S0: init state from inputs (re-done every launch -> deterministic)
    for (int i = bid*256 + tid; i < Bb*Hh; i += NB*256) {
        h0b[i] = ih[i];            h1v[i] = ih[Bb*Hh + i];
        c0b[i] = ic[i];            c1b[i] = ic[Bb*Hh + i];
    }
    gsync(cnt, gen, NB);

    for (int t = 0; t < TDn; ++t) {
        const int p = t & 1;
        const float* h1r = h1v + p*(Bb*Hh);
        float*       h1w = h1v + (p^1)*(Bb*Hh);
        const float* h0r = h0b + p*(Bb*Hh);
        float*       h0w = h0b + (p^1)*(Bb*Hh);

        // ---- S1: q = h1 @ W2^T + b2 ----
        {
            const int b = W >> 6, jg = W & 63;
            f32x4 ha = *(const f32x4*)(h1r + b*Hh + k0);
            f32x4 hb = *(const f32x4*)(h1r + b*Hh + k0 + 4);
            #pragma unroll
            for (int i = 0; i < 8; ++i) {
                const int j = (jg << 3) + i;
                const float* wr = W2w + (size_t)j*Hh + k0;
                float s = dot4(ha, *(const f32x4*)wr) + dot4(hb, *(const f32x4*)(wr + 4));
                s = wsum(s);
                if (l == 0) qb[b*Hh + j] = s + W2b[j];
            }
        }
        gsync(cnt, gen, NB);

        // ---- S2: scores = tanh(encP + q) . v  (masked) ----
        {
            const int b = W >> 6, e0 = (W & 63) << 2;
            f32x4 qa = *(const f32x4*)(qb + b*Hh + k0);
            f32x4 qd = *(const f32x4*)(qb + b*Hh + k0 + 4);
            f32x4 va = *(const f32x4*)(vw + k0);
            f32x4 vd = *(const f32x4*)(vw + k0 + 4);
            #pragma unroll
            for (int i = 0; i < 4; ++i) {
                const int e = e0 + i;
                const float* ep = encP + ((size_t)(b*TEn + e))*Hh + k0;
                f32x4 ea = *(const f32x4*)ep, ed = *(const f32x4*)(ep + 4);
                float s = 0.f;
                #pragma unroll
                for (int c = 0; c < 4; ++c)
                    s += tanhfast(ea[c] + qa[c]) * va[c] + tanhfast(ed[c] + qd[c]) * vd[c];
                s = wsum(s);
                if (l == 0) sc[b*TEn + e] = (smask[b*TEn + e] == 0) ? -1e9f : (s + vb[0]);
            }
        }
        gsync(cnt, gen, NB);

        // ---- S3: softmax + context (uses encT) ----
        {
            const int b = W >> 6, hh0 = (W & 63) << 3;
            f32x4 s4 = *(const f32x4*)(sc + b*TEn + (l << 2));
            float mx = fmaxf(fmaxf(s4[0], s4[1]), fmaxf(s4[2], s4[3]));
            mx = wmax(mx);
            f32x4 e4; float sm = 0.f;
            #pragma unroll
            for (int c = 0; c < 4; ++c) { e4[c] = __expf(s4[c] - mx); sm += e4[c]; }
            sm = wsum(sm);
            const float inv = 1.0f / sm;
            #pragma unroll
            for (int i = 0; i < 8; ++i) {
                const int h = hh0 + i;
                f32x4 en = *(const f32x4*)(encT + ((size_t)(b*Hh + h))*TEn + (l << 2));
                float s = dot4(e4, en);
                s = wsum(s);
                if (l == 0) ctx[b*Hh + h] = s * inv;
            }
        }
        gsync(cnt, gen, NB);

        // ---- S4: LSTM layer 0 (emb-part precomputed in g0e) ----
        {
            const int j = W >> 1, bh = (W & 1) << 3;
            f32x4 wiA[4], wiB[4], whA[4], whB[4];
            #pragma unroll
            for (int g = 0; g < 4; ++g) {
                const float* wi = Wi0 + (size_t)(g*Hh + j)*(Ee + Hh) + Ee + k0;
                wiA[g] = *(const f32x4*)wi; wiB[g] = *(const f32x4*)(wi + 4);
                const float* wh = Wh0 + (size_t)(g*Hh + j)*Hh + k0;
                whA[g] = *(const f32x4*)wh; whB[g] = *(const f32x4*)(wh + 4);
            }
            for (int b = bh; b < bh + 8; ++b) {
                f32x4 xa = *(const f32x4*)(ctx + b*Hh + k0), xd = *(const f32x4*)(ctx + b*Hh + k0 + 4);
                f32x4 hA = *(const f32x4*)(h0r + b*Hh + k0), hd = *(const f32x4*)(h0r + b*Hh + k0 + 4);
                float s0 = dot4(wiA[0],xa)+dot4(wiB[0],xd)+dot4(whA[0],hA)+dot4(whB[0],hd);
                float s1 = dot4(wiA[1],xa)+dot4(wiB[1],xd)+dot4(whA[1],hA)+dot4(whB[1],hd);
                float s2 = dot4(wiA[2],xa)+dot4(wiB[2],xd)+dot4(whA[2],hA)+dot4(whB[2],hd);
                float s3 = dot4(wiA[3],xa)+dot4(wiB[3],xd)+dot4(whA[3],hA)+dot4(whB[3],hd);
                for (int m = 32; m; m >>= 1) {
                    s0 += __shfl_xor(s0, m, 64); s1 += __shfl_xor(s1, m, 64);
                    s2 += __shfl_xor(s2, m, 64); s3 += __shfl_xor(s3, m, 64);
                }
                const float* ge = g0e + ((size_t)(t*Bb + b))*(4*Hh) + j;
                float ii = sigm(s0 + ge[0]);
                float ff = sigm(s1 + ge[Hh]);
                float gg = tanhfast(s2 + ge[2*Hh]);
                float oo = sigm(s3 + ge[3*Hh]);
                if (l == 0) {
                    float c = c0b[b*Hh + j];
                    float cn = ff*c + ii*gg;
                    c0b[b*Hh + j] = cn;
                    h0w[b*Hh + j] = oo * tanhfast(cn);
                }
            }
        }
        gsync(cnt, gen, NB);

        // ---- S5: LSTM layer 1 + bf16 h1 store for fc ----
        {
            const int j = W >> 1, bh = (W & 1) << 3;
            f32x4 wiA[4], wiB[4], whA[4], whB[4];
            float bb[4];
            #pragma unroll
            for (int g = 0; g < 4; ++g) {
                const float* wi = Wi1 + (size_t)(g*Hh + j)*Hh + k0;
                wiA[g] = *(const f32x4*)wi; wiB[g] = *(const f32x4*)(wi + 4);
                const float* wh = Wh1 + (size_t)(g*Hh + j)*Hh + k0;
                whA[g] = *(const f32x4*)wh; whB[g] = *(const f32x4*)(wh + 4);
                bb[g] = bi1[g*Hh + j] + bh1[g*Hh + j];
            }
            for (int b = bh; b < bh + 8; ++b) {
                f32x4 xa = *(const f32x4*)(h0w + b*Hh + k0), xd = *(const f32x4*)(h0w + b*Hh + k0 + 4);
                f32x4 hA = *(const f32x4*)(h1r + b*Hh + k0), hd = *(const f32x4*)(h1r + b*Hh + k0 + 4);
                float s0 = dot4(wiA[0],xa)+dot4(wiB[0],xd)+dot4(whA[0],hA)+dot4(whB[0],hd);
                float s1 = dot4(wiA[1],xa)+dot4(wiB[1],xd)+dot4(whA[1],hA)+dot4(whB[1],hd);
                float s2 = dot4(wiA[2],xa)+dot4(wiB[2],xd)+dot4(whA[2],hA)+dot4(whB[2],hd);
                float s3 = dot4(wiA[3],xa)+dot4(wiB[3],xd)+dot4(whA[3],hA)+dot4(whB[3],hd);
                for (int m = 32; m; m >>= 1) {
                    s0 += __shfl_xor(s0, m, 64); s1 += __shfl_xor(s1, m, 64);
                    s2 += __shfl_xor(s2, m, 64); s3 += __shfl_xor(s3, m, 64);
                }
                float ii = sigm(s0 + bb[0]);
                float ff = sigm(s1 + bb[1]);
                float gg = tanhfast(s2 + bb[2]);
                float oo = sigm(s3 + bb[3]);
                if (l == 0) {
                    float c = c1b[b*Hh + j];
                    float cn = ff*c + ii*gg;
                    c1b[b*Hh + j] = cn;
                    float hn = oo * tanhfast(cn);
                    h1w[b*Hh + j] = hn;
                    h1bf[((size_t)(t*Bb + b))*Hh + j] = f2bf(hn);
                }
            }
        }
        gsync(cnt, gen, NB);
    }
}

extern "C" void kernel_launch(void* const* d_in, const int* in_sizes, int n_in,
                              void* d_out, int out_size, void* d_ws, size_t ws_size,
                              hipStream_t stream)
{
    const int*   ids  = (const int*)d_in[0];
    const float* ih   = (const float*)d_in[1];
    const float* ic   = (const float*)d_in[2];
    const float* enc  = (const float*)d_in[3];
    const int*   smask= (const int*)d_in[4];
    const float* emb  = (const float*)d_in[5];
    const float* W1w  = (const float*)d_in[6];
    const float* W1b  = (const float*)d_in[7];
    const float* W2w  = (const float*)d_in[8];
    const float* W2b  = (const float*)d_in[9];
    const float* vw   = (const float*)d_in[10];
    const float* vb   = (const float*)d_in[11];
    const float* Wi0  = (const float*)d_in[12];
    const float* Wh0  = (const float*)d_in[13];
    const float* bi0  = (const float*)d_in[14];
    const float* bh0  = (const float*)d_in[15];
    const float* Wi1  = (const float*)d_in[16];
    const float* Wh1  = (const float*)d_in[17];
    const float* bi1  = (const float*)d_in[18];
    const float* bh1  = (const float*)d_in[19];
    const float* fcw  = (const float*)d_in[20];
    const float* fcb  = (const float*)d_in[21];
    float* out = (float*)d_out;
    char*  ws  = (char*)d_ws;

    // barrier counters must start at 0 (ws is poisoned 0xAA before timing)
    hipMemsetAsync(ws + OFF_SYNC, 0, 256, stream);

    // prep: fc_w -> bf16 (padded)
    prep_fcw_kernel<<<dim3((unsigned)((size_t)NPAD*Hh/8/256)), dim3(256), 0, stream>>>(
        fcw, (unsigned short*)(ws + OFF_FCWB));

    // prep: enc transpose
    transpose_kernel<<<dim3(TEn/32, Hh/32, Bb), dim3(32, 8), 0, stream>>>(
        enc, (float*)(ws + OFF_ENCT));

    // enc_proj = enc @ W1^T + b1
    gemm_bt<0,0,0><<<dim3(Hh/128, (Bb*TEn)/128), dim3(256), 0, stream>>>(
        enc, W1w, W1b, nullptr, (float*)(ws + OFF_ENCP),
        Bb*TEn, Hh, Hh, Hh, nullptr, 0);

    // g0_emb = emb[ids] @ W_ih0[:, :E]^T + b_ih0 + b_hh0
    gemm_bt<0,1,0><<<dim3((4*Hh)/128, (TDn*Bb)/128), dim3(256), 0, stream>>>(
        emb, Wi0, bi0, bh0, (float*)(ws + OFF_G0E),
        TDn*Bb, 4*Hh, Ee, Ee + Hh, ids, 0);

    // sequential recurrence (cooperative)
    {
        void* args[] = { (void*)&ih, (void*)&ic, (void*)&W2w, (void*)&W2b,
                         (void*)&vw, (void*)&vb, (void*)&smask,
                         (void*)&Wi0, (void*)&Wh0, (void*)&Wi1, (void*)&Wh1,
                         (void*)&bi1, (void*)&bh1, (void*)&ws };
        hipLaunchCooperativeKernel((void*)recur_kernel, dim3(256), dim3(256), args, 0, stream);
    }

    // logits = h1_all @ fc_w^T + fc_b   (batched over all 64 steps)
    gemm_bt<1,0,1><<<dim3(NPAD/128, (TDn*Bb)/128), dim3(256), 0, stream>>>(
        ws + OFF_H1B, ws + OFF_FCWB, fcb, nullptr, out,
        TDn*Bb, NPAD, Hh, Hh, nullptr, Vv);
}

// Round 2
// 4893.462 us; speedup vs baseline: 1.9252x; 1.9252x over previous
//
#include <hip/hip_runtime.h>

#define DI __device__ __forceinline__

typedef __attribute__((ext_vector_type(4))) float f32x4;
typedef __attribute__((ext_vector_type(8))) short bf16x8;
typedef __attribute__((ext_vector_type(8))) unsigned short u16x8;

constexpr int Vv = 50257, NPAD = 50304, Ee = 512, Hh = 512, Bb = 16, TDn = 64, TEn = 256;
constexpr int NBLK = 64;   // recurrence blocks (8 per XCD), 512 thr each -> 512 waves

// ---- workspace layout (bytes) ----
constexpr size_t OFF_ENCP = 0;                                          // (B*TE, H) f32
constexpr size_t OFF_ENCT = OFF_ENCP + (size_t)Bb*TEn*Hh*4;             // (B, H, TE) f32
constexpr size_t OFF_G0E  = OFF_ENCT + (size_t)Bb*Hh*TEn*4;             // (TD*B, 4H) f32
constexpr size_t OFF_FCWB = OFF_G0E  + (size_t)TDn*Bb*4*Hh*4;           // (NPAD, H) bf16
constexpr size_t OFF_H1B  = OFF_FCWB + (size_t)NPAD*Hh*2;               // (TD*B, H) bf16
constexpr size_t OFF_Q    = OFF_H1B  + (size_t)TDn*Bb*Hh*2;             // (B, H) f32
constexpr size_t OFF_SC   = OFF_Q    + (size_t)Bb*Hh*4;                 // (B, TE) f32
constexpr size_t OFF_CTX  = OFF_SC   + (size_t)Bb*TEn*4;                // (B, H) f32
constexpr size_t OFF_H0   = OFF_CTX  + (size_t)Bb*Hh*4;                 // 2x (B,H)
constexpr size_t OFF_H1   = OFF_H0   + (size_t)2*Bb*Hh*4;               // 2x (B,H)
constexpr size_t OFF_SYNC = OFF_H1   + (size_t)2*Bb*Hh*4;               // 2 KiB sync area

DI float dot4(f32x4 a, f32x4 b) { return a[0]*b[0] + a[1]*b[1] + a[2]*b[2] + a[3]*b[3]; }
DI float wsum(float v) { for (int m = 32; m; m >>= 1) v += __shfl_xor(v, m, 64); return v; }
DI float wmax(float v) { for (int m = 32; m; m >>= 1) v = fmaxf(v, __shfl_xor(v, m, 64)); return v; }
DI void wsum4(float& a, float& b, float& c, float& d) {
    #pragma unroll
    for (int m = 32; m; m >>= 1) {
        a += __shfl_xor(a, m, 64);
        b += __shfl_xor(b, m, 64);
        c += __shfl_xor(c, m, 64);
        d += __shfl_xor(d, m, 64);
    }
}
DI float tanhfast(float x) { float e = __expf(2.f * x); return 1.f - 2.f / (e + 1.f); }
DI float sigm(float x) { return 1.f / (1.f + __expf(-x)); }

DI unsigned short f2bf(float f) {
    unsigned u = __builtin_bit_cast(unsigned, f);
    unsigned r = (u + 0x7FFFu + ((u >> 16) & 1u)) >> 16;
    return (unsigned short)r;
}
DI u16x8 cvt8(f32x4 a, f32x4 b) {
    u16x8 r;
    r[0]=f2bf(a[0]); r[1]=f2bf(a[1]); r[2]=f2bf(a[2]); r[3]=f2bf(a[3]);
    r[4]=f2bf(b[0]); r[5]=f2bf(b[1]); r[6]=f2bf(b[2]); r[7]=f2bf(b[3]);
    return r;
}

// ---- hierarchical grid barrier: 8 sub-counters (8 blocks each) -> root -> gen ----
// sync area layout (uints): gen @0, root @32, sub[s] @64+s*32  (128B line spacing)
DI void gsync(unsigned* sy, int bid) {
    __syncthreads();
    if (threadIdx.x == 0) {
        unsigned* gen  = sy;
        unsigned* root = sy + 32;
        unsigned* sub  = sy + 64 + ((bid & 7) << 5);
        __threadfence();
        unsigned g = __hip_atomic_load(gen, __ATOMIC_RELAXED, __HIP_MEMORY_SCOPE_AGENT);
        bool released = false;
        if (__hip_atomic_fetch_add(sub, 1u, __ATOMIC_ACQ_REL, __HIP_MEMORY_SCOPE_AGENT) == 7u) {
            __hip_atomic_store(sub, 0u, __ATOMIC_RELAXED, __HIP_MEMORY_SCOPE_AGENT);
            if (__hip_atomic_fetch_add(root, 1u, __ATOMIC_ACQ_REL, __HIP_MEMORY_SCOPE_AGENT) == 7u) {
                __hip_atomic_store(root, 0u, __ATOMIC_RELAXED, __HIP_MEMORY_SCOPE_AGENT);
                __hip_atomic_store(gen, g + 1u, __ATOMIC_RELEASE, __HIP_MEMORY_SCOPE_AGENT);
                released = true;
            }
        }
        if (!released) {
            while (__hip_atomic_load(gen, __ATOMIC_ACQUIRE, __HIP_MEMORY_SCOPE_AGENT) == g)
                __builtin_amdgcn_s_sleep(8);
        }
        __threadfence();
    }
    __syncthreads();
}

// ---- prep: fc_w f32 -> bf16, padded to NPAD rows ----
__global__ void prep_fcw_kernel(const float* __restrict__ src, unsigned short* __restrict__ dst) {
    size_t i = ((size_t)blockIdx.x * 256 + threadIdx.x) << 3;
    int n = (int)(i >> 9);
    u16x8 v = {0,0,0,0,0,0,0,0};
    if (n < Vv) {
        const float* p = src + i;
        v = cvt8(*(const f32x4*)p, *(const f32x4*)(p + 4));
    }
    *(u16x8*)(dst + i) = v;
}

// ---- prep: enc (B,TE,H) -> encT (B,H,TE) ----
__global__ void transpose_kernel(const float* __restrict__ enc, float* __restrict__ encT) {
    __shared__ float tile[32][33];
    const int b = blockIdx.z, e0 = blockIdx.x << 5, h0 = blockIdx.y << 5;
    const int tx = threadIdx.x, ty = threadIdx.y;  // 32 x 8
    #pragma unroll
    for (int i = 0; i < 4; ++i)
        tile[ty + i*8][tx] = enc[((size_t)(b*TEn + e0 + ty + i*8))*Hh + h0 + tx];
    __syncthreads();
    #pragma unroll
    for (int i = 0; i < 4; ++i)
        encT[((size_t)(b*Hh + h0 + ty + i*8))*TEn + e0 + tx] = tile[tx][ty + i*8];
}

// ---- MFMA bf16 GEMM: C[m][n] = sum_k A[m][k]*B[n][k] (+bias), 128x128x32 tiles ----
template<int SRCBF, int GATHER, int OUTM>
__global__ __launch_bounds__(256, 2) void gemm_bt(
    const void* __restrict__ Av, const void* __restrict__ Bv,
    const float* __restrict__ bias, const float* __restrict__ bias2,
    float* __restrict__ Cout, int M, int N, int K, int ldb,
    const int* __restrict__ ids, int NV)
{
    __shared__ unsigned short As[128*32], Bs[128*32];
    const int tid = threadIdx.x;
    const int bn = blockIdx.x, bm = blockIdx.y;
    const int w = tid >> 6, l = tid & 63;
    const int wm = w >> 1, wn = w & 1;
    const int lr = l & 15, ls = l >> 4;
    f32x4 acc[4][4] = {};

    const int r0 = tid >> 2, c0 = (tid & 3) << 3;

    for (int kb = 0; kb < K; kb += 32) {
        #pragma unroll
        for (int half = 0; half < 2; ++half) {
            const int rr = r0 + half*64;
            {   // A tile
                const int gm = bm*128 + rr;
                size_t arow = GATHER ? (size_t)ids[((gm & 15) << 6) + (gm >> 4)] : (size_t)gm;
                u16x8 v;
                if (SRCBF) {
                    v = *(const u16x8*)((const unsigned short*)Av + arow*(size_t)K + kb + c0);
                } else {
                    const float* ap = (const float*)Av + arow*(size_t)K + kb + c0;
                    v = cvt8(*(const f32x4*)ap, *(const f32x4*)(ap + 4));
                }
                *(u16x8*)&As[rr*32 + c0] = v;
            }
            {   // B tile
                const size_t brow = (size_t)(bn*128 + rr);
                u16x8 v;
                if (SRCBF) {
                    v = *(const u16x8*)((const unsigned short*)Bv + brow*(size_t)ldb + kb + c0);
                } else {
                    const float* bp = (const float*)Bv + brow*(size_t)ldb + kb + c0;
                    v = cvt8(*(const f32x4*)bp, *(const f32x4*)(bp + 4));
                }
                *(u16x8*)&Bs[rr*32 + c0] = v;
            }
        }
        __syncthreads();
        bf16x8 af[4], bfv[4];
        #pragma unroll
        for (int mt = 0; mt < 4; ++mt) af[mt]  = *(const bf16x8*)&As[(wm*64 + mt*16 + lr)*32 + ls*8];
        #pragma unroll
        for (int nt = 0; nt < 4; ++nt) bfv[nt] = *(const bf16x8*)&Bs[(wn*64 + nt*16 + lr)*32 + ls*8];
        #pragma unroll
        for (int mt = 0; mt < 4; ++mt)
            #pragma unroll
            for (int nt = 0; nt < 4; ++nt)
                acc[mt][nt] = __builtin_amdgcn_mfma_f32_16x16x32_bf16(af[mt], bfv[nt], acc[mt][nt], 0, 0, 0);
        __syncthreads();
    }

    #pragma unroll
    for (int mt = 0; mt < 4; ++mt) {
        #pragma unroll
        for (int nt = 0; nt < 4; ++nt) {
            const int n = bn*128 + wn*64 + nt*16 + lr;
            const int mbase = bm*128 + wm*64 + mt*16 + ls*4;
            f32x4 a = acc[mt][nt];
            #pragma unroll
            for (int r = 0; r < 4; ++r) {
                const int m = mbase + r;
                if (OUTM == 0) {
                    float v = a[r] + bias[n] + (bias2 ? bias2[n] : 0.f);
                    Cout[(size_t)m*N + n] = v;
                } else {
                    if (n < NV) {
                        float v = a[r] + bias[n];
                        Cout[(size_t)(((m & 15) << 6) + (m >> 4))*NV + n] = v;
                    }
                }
            }
        }
    }
}

// ---- cooperative recurrence: 64 blocks x 512 thr; wave j owns gate-row j; weights in VGPRs ----
__global__ __launch_bounds__(512, 2) void recur_kernel(
    const float* __restrict__ ih, const float* __restrict__ ic,
    const float* __restrict__ W2w, const float* __restrict__ W2b,
    const float* __restrict__ vw, const float* __restrict__ vb,
    const int* __restrict__ smask,
    const float* __restrict__ Wi0, const float* __restrict__ Wh0,
    const float* __restrict__ Wi1, const float* __restrict__ Wh1,
    const float* __restrict__ bi1, const float* __restrict__ bh1,
    char* __restrict__ ws)
{
    float* encP = (float*)(ws + OFF_ENCP);
    float* encT = (float*)(ws + OFF_ENCT);
    float* g0e  = (float*)(ws + OFF_G0E);
    unsigned short* h1bf = (unsigned short*)(ws + OFF_H1B);
    float* qb  = (float*)(ws + OFF_Q);
    float* sc  = (float*)(ws + OFF_SC);
    float* ctx = (float*)(ws + OFF_CTX);
    float* h0b = (float*)(ws + OFF_H0);
    float* h1v = (float*)(ws + OFF_H1);
    unsigned* sy = (unsigned*)(ws + OFF_SYNC);

    __shared__ float lds[2 * Bb * Hh];   // 64 KiB staging

    const int tid = threadIdx.x, bid = blockIdx.x;
    const int wid = tid >> 6, l = tid & 63;
    const int j  = (bid << 3) + wid;     // owned column / global wave id, 0..511
    const int k0 = l << 3;               // lane k-slice (8 floats)

    // ---- persistent per-lane LSTM weight fragments (128 VGPRs) ----
    f32x4 wi0a[4], wi0b[4], wh0a[4], wh0b[4];
    f32x4 wi1a[4], wi1b[4], wh1a[4], wh1b[4];
    float bb1[4];
    #pragma unroll
    for (int g = 0; g < 4; ++g) {
        const float* p0 = Wi0 + (size_t)(g*Hh + j)*(Ee + Hh) + Ee + k0;
        wi0a[g] = *(const f32x4*)p0; wi0b[g] = *(const f32x4*)(p0 + 4);
        const float* p1 = Wh0 + (size_t)(g*Hh + j)*Hh + k0;
        wh0a[g] = *(const f32x4*)p1; wh0b[g] = *(const f32x4*)(p1 + 4);
        const float* p2 = Wi1 + (size_t)(g*Hh + j)*Hh + k0;
        wi1a[g] = *(const f32x4*)p2; wi1b[g] = *(const f32x4*)(p2 + 4);
        const float* p3 = Wh1 + (size_t)(g*Hh + j)*Hh + k0;
        wh1a[g] = *(const f32x4*)p3; wh1b[g] = *(const f32x4*)(p3 + 4);
        bb1[g] = bi1[g*Hh + j] + bh1[g*Hh + j];
    }
    // cell state lives in lane b (b = l < 16)
    float c0r = (l < 16) ? ic[l*Hh + j]           : 0.f;
    float c1r = (l < 16) ? ic[Bb*Hh + l*Hh + j]   : 0.f;

    // init h double-buffers (parity 0)
    for (int i = bid*512 + tid; i < Bb*Hh; i += NBLK*512) {
        h0b[i] = ih[i];
        h1v[i] = ih[Bb*Hh + i];
    }
    gsync(sy, bid);

    const int sb = j >> 5;              // batch for scores/ctx phases
    const int se0 = (j & 31) << 3;      // 8 score rows
    const int ch0 = (j & 31) << 4;      // 16 ctx outputs

    for (int t = 0; t < TDn; ++t) {
        const int p = t & 1;
        const float* h1r = h1v + p*(Bb*Hh);
        float*       h1w = h1v + (p^1)*(Bb*Hh);
        const float* h0r = h0b + p*(Bb*Hh);
        float*       h0w = h0b + (p^1)*(Bb*Hh);

        // ================= phase 1: q = h1 @ W2^T + b2 =================
        {
            for (int i = tid*4; i < Bb*Hh; i += 2048)
                *(f32x4*)&lds[i] = *(const f32x4*)&h1r[i];
            __syncthreads();
            const float* wr = W2w + (size_t)j*Hh + k0;
            f32x4 w2a = *(const f32x4*)wr, w2d = *(const f32x4*)(wr + 4);
            float w2bias = W2b[j];
            float qv = 0.f;
            #pragma unroll 4
            for (int b = 0; b < Bb; ++b) {
                f32x4 ha = *(const f32x4*)&lds[b*Hh + k0];
                f32x4 hd = *(const f32x4*)&lds[b*Hh + k0 + 4];
                float s = dot4(ha, w2a) + dot4(hd, w2d);
                s = wsum(s);
                qv = (l == b) ? s + w2bias : qv;
            }
            if (l < 16) qb[l*Hh + j] = qv;
        }
        gsync(sy, bid);

        // ================= phase 2: scores = tanh(encP + q).v (masked) =================
        {
            f32x4 qa = *(const f32x4*)&qb[sb*Hh + k0];
            f32x4 qd = *(const f32x4*)&qb[sb*Hh + k0 + 4];
            f32x4 va = *(const f32x4*)&vw[k0];
            f32x4 vd = *(const f32x4*)&vw[k0 + 4];
            float vbias = vb[0];
            float myS = 0.f;
            #pragma unroll
            for (int i = 0; i < 8; ++i) {
                const int e = se0 + i;
                const float* ep = encP + ((size_t)(sb*TEn + e))*Hh + k0;
                f32x4 ea = *(const f32x4*)ep, ed = *(const f32x4*)(ep + 4);
                float s = 0.f;
                #pragma unroll
                for (int c = 0; c < 4; ++c)
                    s += tanhfast(ea[c] + qa[c]) * va[c] + tanhfast(ed[c] + qd[c]) * vd[c];
                s = wsum(s);
                myS = (l == i) ? s : myS;
            }
            if (l < 8) {
                const int e = se0 + l;
                sc[sb*TEn + e] = (smask[sb*TEn + e] == 0) ? -1e9f : (myS + vbias);
            }
        }
        gsync(sy, bid);

        // ================= phase 3: softmax + context =================
        {
            f32x4 s4 = *(const f32x4*)&sc[sb*TEn + (l << 2)];
            float mx = wmax(fmaxf(fmaxf(s4[0], s4[1]), fmaxf(s4[2], s4[3])));
            f32x4 e4; float sm = 0.f;
            #pragma unroll
            for (int c = 0; c < 4; ++c) { e4[c] = __expf(s4[c] - mx); sm += e4[c]; }
            sm = wsum(sm);
            const float inv = 1.0f / sm;
            float myC = 0.f;
            #pragma unroll 4
            for (int i = 0; i < 16; ++i) {
                const int h = ch0 + i;
                f32x4 en = *(const f32x4*)&encT[((size_t)(sb*Hh + h))*TEn + (l << 2)];
                float s = wsum(dot4(e4, en));
                myC = (l == i) ? s : myC;
            }
            if (l < 16) ctx[sb*Hh + ch0 + l] = myC * inv;
        }
        gsync(sy, bid);

        // ================= phase 4: LSTM layer 0 =================
        {
            // prefetch per-lane g0e (emb-part gates, biases folded in)
            float ge0 = 0.f, ge1 = 0.f, ge2 = 0.f, ge3 = 0.f;
            if (l < 16) {
                const float* gp = g0e + ((size_t)(t*Bb + l))*(4*Hh) + j;
                ge0 = gp[0]; ge1 = gp[Hh]; ge2 = gp[2*Hh]; ge3 = gp[3*Hh];
            }
            for (int i = tid*4; i < Bb*Hh; i += 2048) {
                *(f32x4*)&lds[i]          = *(const f32x4*)&ctx[i];
                *(f32x4*)&lds[Bb*Hh + i]  = *(const f32x4*)&h0r[i];
            }
            __syncthreads();
            float ls0 = 0.f, ls1 = 0.f, ls2 = 0.f, ls3 = 0.f;
            #pragma unroll 4
            for (int b = 0; b < Bb; ++b) {
                f32x4 xa = *(const f32x4*)&lds[b*Hh + k0];
                f32x4 xd = *(const f32x4*)&lds[b*Hh + k0 + 4];
                f32x4 ha = *(const f32x4*)&lds[Bb*Hh + b*Hh + k0];
                f32x4 hd = *(const f32x4*)&lds[Bb*Hh + b*Hh + k0 + 4];
                float s0 = dot4(wi0a[0],xa)+dot4(wi0b[0],xd)+dot4(wh0a[0],ha)+dot4(wh0b[0],hd);
                float s1 = dot4(wi0a[1],xa)+dot4(wi0b[1],xd)+dot4(wh0a[1],ha)+dot4(wh0b[1],hd);
                float s2 = dot4(wi0a[2],xa)+dot4(wi0b[2],xd)+dot4(wh0a[2],ha)+dot4(wh0b[2],hd);
                float s3 = dot4(wi0a[3],xa)+dot4(wi0b[3],xd)+dot4(wh0a[3],ha)+dot4(wh0b[3],hd);
                wsum4(s0, s1, s2, s3);
                if (l == b) { ls0 = s0; ls1 = s1; ls2 = s2; ls3 = s3; }
            }
            if (l < 16) {
                float ii = sigm(ls0 + ge0), ff = sigm(ls1 + ge1);
                float gg = tanhfast(ls2 + ge2), oo = sigm(ls3 + ge3);
                float cn = ff*c0r + ii*gg;
                c0r = cn;
                h0w[l*Hh + j] = oo * tanhfast(cn);
            }
        }
        gsync(sy, bid);

        // ================= phase 5: LSTM layer 1 + bf16 h1 store =================
        {
            for (int i = tid*4; i < Bb*Hh; i += 2048) {
                *(f32x4*)&lds[i]          = *(const f32x4*)&h0w[i];
                *(f32x4*)&lds[Bb*Hh + i]  = *(const f32x4*)&h1r[i];
            }
            __syncthreads();
            float ls0 = 0.f, ls1 = 0.f, ls2 = 0.f, ls3 = 0.f;
            #pragma unroll 4
            for (int b = 0; b < Bb; ++b) {
                f32x4 xa = *(const f32x4*)&lds[b*Hh + k0];
                f32x4 xd = *(const f32x4*)&lds[b*Hh + k0 + 4];
                f32x4 ha = *(const f32x4*)&lds[Bb*Hh + b*Hh + k0];
                f32x4 hd = *(const f32x4*)&lds[Bb*Hh + b*Hh + k0 + 4];
                float s0 = dot4(wi1a[0],xa)+dot4(wi1b[0],xd)+dot4(wh1a[0],ha)+dot4(wh1b[0],hd);
                float s1 = dot4(wi1a[1],xa)+dot4(wi1b[1],xd)+dot4(wh1a[1],ha)+dot4(wh1b[1],hd);
                float s2 = dot4(wi1a[2],xa)+dot4(wi1b[2],xd)+dot4(wh1a[2],ha)+dot4(wh1b[2],hd);
                float s3 = dot4(wi1a[3],xa)+dot4(wi1b[3],xd)+dot4(wh1a[3],ha)+dot4(wh1b[3],hd);
                wsum4(s0, s1, s2, s3);
                if (l == b) { ls0 = s0; ls1 = s1; ls2 = s2; ls3 = s3; }
            }
            if (l < 16) {
                float ii = sigm(ls0 + bb1[0]), ff = sigm(ls1 + bb1[1]);
                float gg = tanhfast(ls2 + bb1[2]), oo = sigm(ls3 + bb1[3]);
                float cn = ff*c1r + ii*gg;
                c1r = cn;
                float hn = oo * tanhfast(cn);
                h1w[l*Hh + j] = hn;
                h1bf[((size_t)(t*Bb + l))*Hh + j] = f2bf(hn);
            }
        }
        gsync(sy, bid);
    }
}

extern "C" void kernel_launch(void* const* d_in, const int* in_sizes, int n_in,
                              void* d_out, int out_size, void* d_ws, size_t ws_size,
                              hipStream_t stream)
{
    const int*   ids  = (const int*)d_in[0];
    const float* ih   = (const float*)d_in[1];
    const float* ic   = (const float*)d_in[2];
    const float* enc  = (const float*)d_in[3];
    const int*   smask= (const int*)d_in[4];
    const float* emb  = (const float*)d_in[5];
    const float* W1w  = (const float*)d_in[6];
    const float* W1b  = (const float*)d_in[7];
    const float* W2w  = (const float*)d_in[8];
    const float* W2b  = (const float*)d_in[9];
    const float* vw   = (const float*)d_in[10];
    const float* vb   = (const float*)d_in[11];
    const float* Wi0  = (const float*)d_in[12];
    const float* Wh0  = (const float*)d_in[13];
    const float* bi0  = (const float*)d_in[14];
    const float* bh0  = (const float*)d_in[15];
    const float* Wi1  = (const float*)d_in[16];
    const float* Wh1  = (const float*)d_in[17];
    const float* bi1  = (const float*)d_in[18];
    const float* bh1  = (const float*)d_in[19];
    const float* fcw  = (const float*)d_in[20];
    const float* fcb  = (const float*)d_in[21];
    float* out = (float*)d_out;
    char*  ws  = (char*)d_ws;

    // barrier counters must start at 0 (ws is poisoned 0xAA before timing)
    hipMemsetAsync(ws + OFF_SYNC, 0, 2048, stream);

    // prep: fc_w -> bf16 (padded)
    prep_fcw_kernel<<<dim3((unsigned)((size_t)NPAD*Hh/8/256)), dim3(256), 0, stream>>>(
        fcw, (unsigned short*)(ws + OFF_FCWB));

    // prep: enc transpose
    transpose_kernel<<<dim3(TEn/32, Hh/32, Bb), dim3(32, 8), 0, stream>>>(
        enc, (float*)(ws + OFF_ENCT));

    // enc_proj = enc @ W1^T + b1
    gemm_bt<0,0,0><<<dim3(Hh/128, (Bb*TEn)/128), dim3(256), 0, stream>>>(
        enc, W1w, W1b, nullptr, (float*)(ws + OFF_ENCP),
        Bb*TEn, Hh, Hh, Hh, nullptr, 0);

    // g0_emb = emb[ids] @ W_ih0[:, :E]^T + b_ih0 + b_hh0
    gemm_bt<0,1,0><<<dim3((4*Hh)/128, (TDn*Bb)/128), dim3(256), 0, stream>>>(
        emb, Wi0, bi0, bh0, (float*)(ws + OFF_G0E),
        TDn*Bb, 4*Hh, Ee, Ee + Hh, ids, 0);

    // sequential recurrence (cooperative, 64 blocks x 512 threads)
    {
        void* args[] = { (void*)&ih, (void*)&ic, (void*)&W2w, (void*)&W2b,
                         (void*)&vw, (void*)&vb, (void*)&smask,
                         (void*)&Wi0, (void*)&Wh0, (void*)&Wi1, (void*)&Wh1,
                         (void*)&bi1, (void*)&bh1, (void*)&ws };
        hipLaunchCooperativeKernel((void*)recur_kernel, dim3(NBLK), dim3(512), args, 0, stream);
    }

    // logits = h1_all @ fc_w^T + fc_b   (batched over all 64 steps)
    gemm_bt<1,0,1><<<dim3(NPAD/128, (TDn*Bb)/128), dim3(256), 0, stream>>>(
        ws + OFF_H1B, ws + OFF_FCWB, fcb, nullptr, out,
        TDn*Bb, NPAD, Hh, Hh, nullptr, Vv);
}

// Round 3
// 4887.597 us; speedup vs baseline: 1.9275x; 1.0012x over previous
//
#include <hip/hip_runtime.h>

#define DI __device__ __forceinline__

typedef __attribute__((ext_vector_type(4))) float f32x4;
typedef __attribute__((ext_vector_type(8))) short bf16x8;
typedef __attribute__((ext_vector_type(8))) unsigned short u16x8;

constexpr int Vv = 50257, NPAD = 50304, Ee = 512, Hh = 512, Bb = 16, TDn = 64, TEn = 256;
constexpr int NBLK = 64;   // recurrence blocks (8 per XCD), 512 thr each -> 512 waves

// ---- workspace layout (bytes) ----
constexpr size_t OFF_ENCP = 0;                                          // (B*TE, H) f32
constexpr size_t OFF_ENCT = OFF_ENCP + (size_t)Bb*TEn*Hh*4;             // (B, H, TE) f32
constexpr size_t OFF_G0E  = OFF_ENCT + (size_t)Bb*Hh*TEn*4;             // (TD*B, 4H) f32
constexpr size_t OFF_FCWB = OFF_G0E  + (size_t)TDn*Bb*4*Hh*4;           // (NPAD, H) bf16
constexpr size_t OFF_H1B  = OFF_FCWB + (size_t)NPAD*Hh*2;               // (TD*B, H) bf16
constexpr size_t OFF_Q    = OFF_H1B  + (size_t)TDn*Bb*Hh*2;             // (B, H) f32
constexpr size_t OFF_SC   = OFF_Q    + (size_t)Bb*Hh*4;                 // (B, TE) f32
constexpr size_t OFF_CTX  = OFF_SC   + (size_t)Bb*TEn*4;                // (B, H) f32
constexpr size_t OFF_H0   = OFF_CTX  + (size_t)Bb*Hh*4;                 // 2x (B,H)
constexpr size_t OFF_H1   = OFF_H0   + (size_t)2*Bb*Hh*4;               // 2x (B,H)
constexpr size_t OFF_SYNC = OFF_H1   + (size_t)2*Bb*Hh*4;               // 2 KiB sync area

DI float dot4(f32x4 a, f32x4 b) { return a[0]*b[0] + a[1]*b[1] + a[2]*b[2] + a[3]*b[3]; }
DI float wsum(float v) { for (int m = 32; m; m >>= 1) v += __shfl_xor(v, m, 64); return v; }
DI float wmax(float v) { for (int m = 32; m; m >>= 1) v = fmaxf(v, __shfl_xor(v, m, 64)); return v; }
DI void wsum4(float& a, float& b, float& c, float& d) {
    #pragma unroll
    for (int m = 32; m; m >>= 1) {
        a += __shfl_xor(a, m, 64);
        b += __shfl_xor(b, m, 64);
        c += __shfl_xor(c, m, 64);
        d += __shfl_xor(d, m, 64);
    }
}
DI float tanhfast(float x) { float e = __expf(2.f * x); return 1.f - 2.f / (e + 1.f); }
DI float sigm(float x) { return 1.f / (1.f + __expf(-x)); }

// LDS bank-quad spreading swizzle (dword index, preserves 16B blocks)
DI int swz(int a) { return a ^ (((a >> 5) & 7) << 2); }

DI unsigned short f2bf(float f) {
    unsigned u = __builtin_bit_cast(unsigned, f);
    unsigned r = (u + 0x7FFFu + ((u >> 16) & 1u)) >> 16;
    return (unsigned short)r;
}
DI u16x8 cvt8(f32x4 a, f32x4 b) {
    u16x8 r;
    r[0]=f2bf(a[0]); r[1]=f2bf(a[1]); r[2]=f2bf(a[2]); r[3]=f2bf(a[3]);
    r[4]=f2bf(b[0]); r[5]=f2bf(b[1]); r[6]=f2bf(b[2]); r[7]=f2bf(b[3]);
    return r;
}

// ---- hierarchical grid barrier: 8 sub-counters (8 blocks each) -> root -> gen ----
DI void gsync(unsigned* sy, int bid) {
    __syncthreads();
    if (threadIdx.x == 0) {
        unsigned* gen  = sy;
        unsigned* root = sy + 32;
        unsigned* sub  = sy + 64 + ((bid & 7) << 5);
        __threadfence();
        unsigned g = __hip_atomic_load(gen, __ATOMIC_RELAXED, __HIP_MEMORY_SCOPE_AGENT);
        bool released = false;
        if (__hip_atomic_fetch_add(sub, 1u, __ATOMIC_ACQ_REL, __HIP_MEMORY_SCOPE_AGENT) == 7u) {
            __hip_atomic_store(sub, 0u, __ATOMIC_RELAXED, __HIP_MEMORY_SCOPE_AGENT);
            if (__hip_atomic_fetch_add(root, 1u, __ATOMIC_ACQ_REL, __HIP_MEMORY_SCOPE_AGENT) == 7u) {
                __hip_atomic_store(root, 0u, __ATOMIC_RELAXED, __HIP_MEMORY_SCOPE_AGENT);
                __hip_atomic_store(gen, g + 1u, __ATOMIC_RELEASE, __HIP_MEMORY_SCOPE_AGENT);
                released = true;
            }
        }
        if (!released) {
            while (__hip_atomic_load(gen, __ATOMIC_ACQUIRE, __HIP_MEMORY_SCOPE_AGENT) == g)
                __builtin_amdgcn_s_sleep(4);
        }
        __threadfence();
    }
    __syncthreads();
}

// ---- prep: fc_w f32 -> bf16, padded to NPAD rows ----
__global__ void prep_fcw_kernel(const float* __restrict__ src, unsigned short* __restrict__ dst) {
    size_t i = ((size_t)blockIdx.x * 256 + threadIdx.x) << 3;
    int n = (int)(i >> 9);
    u16x8 v = {0,0,0,0,0,0,0,0};
    if (n < Vv) {
        const float* p = src + i;
        v = cvt8(*(const f32x4*)p, *(const f32x4*)(p + 4));
    }
    *(u16x8*)(dst + i) = v;
}

// ---- prep: enc (B,TE,H) -> encT (B,H,TE) ----
__global__ void transpose_kernel(const float* __restrict__ enc, float* __restrict__ encT) {
    __shared__ float tile[32][33];
    const int b = blockIdx.z, e0 = blockIdx.x << 5, h0 = blockIdx.y << 5;
    const int tx = threadIdx.x, ty = threadIdx.y;  // 32 x 8
    #pragma unroll
    for (int i = 0; i < 4; ++i)
        tile[ty + i*8][tx] = enc[((size_t)(b*TEn + e0 + ty + i*8))*Hh + h0 + tx];
    __syncthreads();
    #pragma unroll
    for (int i = 0; i < 4; ++i)
        encT[((size_t)(b*Hh + h0 + ty + i*8))*TEn + e0 + tx] = tile[tx][ty + i*8];
}

// ---- MFMA bf16 GEMM: C[m][n] = sum_k A[m][k]*B[n][k] (+bias), 128x128x32 tiles ----
template<int SRCBF, int GATHER, int OUTM>
__global__ __launch_bounds__(256, 2) void gemm_bt(
    const void* __restrict__ Av, const void* __restrict__ Bv,
    const float* __restrict__ bias, const float* __restrict__ bias2,
    float* __restrict__ Cout, int M, int N, int K, int ldb,
    const int* __restrict__ ids, int NV)
{
    __shared__ unsigned short As[128*32], Bs[128*32];
    const int tid = threadIdx.x;
    const int bn = blockIdx.x, bm = blockIdx.y;
    const int w = tid >> 6, l = tid & 63;
    const int wm = w >> 1, wn = w & 1;
    const int lr = l & 15, ls = l >> 4;
    f32x4 acc[4][4] = {};

    const int r0 = tid >> 2, c0 = (tid & 3) << 3;

    for (int kb = 0; kb < K; kb += 32) {
        #pragma unroll
        for (int half = 0; half < 2; ++half) {
            const int rr = r0 + half*64;
            {   // A tile
                const int gm = bm*128 + rr;
                size_t arow = GATHER ? (size_t)ids[((gm & 15) << 6) + (gm >> 4)] : (size_t)gm;
                u16x8 v;
                if (SRCBF) {
                    v = *(const u16x8*)((const unsigned short*)Av + arow*(size_t)K + kb + c0);
                } else {
                    const float* ap = (const float*)Av + arow*(size_t)K + kb + c0;
                    v = cvt8(*(const f32x4*)ap, *(const f32x4*)(ap + 4));
                }
                *(u16x8*)&As[rr*32 + c0] = v;
            }
            {   // B tile
                const size_t brow = (size_t)(bn*128 + rr);
                u16x8 v;
                if (SRCBF) {
                    v = *(const u16x8*)((const unsigned short*)Bv + brow*(size_t)ldb + kb + c0);
                } else {
                    const float* bp = (const float*)Bv + brow*(size_t)ldb + kb + c0;
                    v = cvt8(*(const f32x4*)bp, *(const f32x4*)(bp + 4));
                }
                *(u16x8*)&Bs[rr*32 + c0] = v;
            }
        }
        __syncthreads();
        bf16x8 af[4], bfv[4];
        #pragma unroll
        for (int mt = 0; mt < 4; ++mt) af[mt]  = *(const bf16x8*)&As[(wm*64 + mt*16 + lr)*32 + ls*8];
        #pragma unroll
        for (int nt = 0; nt < 4; ++nt) bfv[nt] = *(const bf16x8*)&Bs[(wn*64 + nt*16 + lr)*32 + ls*8];
        #pragma unroll
        for (int mt = 0; mt < 4; ++mt)
            #pragma unroll
            for (int nt = 0; nt < 4; ++nt)
                acc[mt][nt] = __builtin_amdgcn_mfma_f32_16x16x32_bf16(af[mt], bfv[nt], acc[mt][nt], 0, 0, 0);
        __syncthreads();
    }

    #pragma unroll
    for (int mt = 0; mt < 4; ++mt) {
        #pragma unroll
        for (int nt = 0; nt < 4; ++nt) {
            const int n = bn*128 + wn*64 + nt*16 + lr;
            const int mbase = bm*128 + wm*64 + mt*16 + ls*4;
            f32x4 a = acc[mt][nt];
            #pragma unroll
            for (int r = 0; r < 4; ++r) {
                const int m = mbase + r;
                if (OUTM == 0) {
                    float v = a[r] + bias[n] + (bias2 ? bias2[n] : 0.f);
                    Cout[(size_t)m*N + n] = v;
                } else {
                    if (n < NV) {
                        float v = a[r] + bias[n];
                        Cout[(size_t)(((m & 15) << 6) + (m >> 4))*NV + n] = v;
                    }
                }
            }
        }
    }
}

// ---- cooperative recurrence: 64 blocks x 512 thr; wave j owns gate-row j; weights in VGPRs ----
__global__ __launch_bounds__(512, 1) void recur_kernel(
    const float* __restrict__ ih, const float* __restrict__ ic,
    const float* __restrict__ W2w, const float* __restrict__ W2b,
    const float* __restrict__ vw, const float* __restrict__ vb,
    const int* __restrict__ smask,
    const float* __restrict__ Wi0, const float* __restrict__ Wh0,
    const float* __restrict__ Wi1, const float* __restrict__ Wh1,
    const float* __restrict__ bi1, const float* __restrict__ bh1,
    char* __restrict__ ws)
{
    float* encP = (float*)(ws + OFF_ENCP);
    float* encT = (float*)(ws + OFF_ENCT);
    float* g0e  = (float*)(ws + OFF_G0E);
    unsigned short* h1bf = (unsigned short*)(ws + OFF_H1B);
    float* qb  = (float*)(ws + OFF_Q);
    float* sc  = (float*)(ws + OFF_SC);
    float* ctx = (float*)(ws + OFF_CTX);
    float* h0b = (float*)(ws + OFF_H0);
    float* h1v = (float*)(ws + OFF_H1);
    unsigned* sy = (unsigned*)(ws + OFF_SYNC);

    __shared__ float lds[2 * Bb * Hh];   // 64 KiB staging

    const int tid = threadIdx.x, bid = blockIdx.x;
    const int wid = tid >> 6, l = tid & 63;
    const int j  = (bid << 3) + wid;     // owned column / global wave id, 0..511
    const int k0 = l << 3;               // lane k-slice (8 floats)

    // ---- persistent per-lane LSTM weight fragments (128 VGPRs) ----
    f32x4 wi0a[4], wi0b[4], wh0a[4], wh0b[4];
    f32x4 wi1a[4], wi1b[4], wh1a[4], wh1b[4];
    float bb1[4];
    #pragma unroll
    for (int g = 0; g < 4; ++g) {
        const float* p0 = Wi0 + (size_t)(g*Hh + j)*(Ee + Hh) + Ee + k0;
        wi0a[g] = *(const f32x4*)p0; wi0b[g] = *(const f32x4*)(p0 + 4);
        const float* p1 = Wh0 + (size_t)(g*Hh + j)*Hh + k0;
        wh0a[g] = *(const f32x4*)p1; wh0b[g] = *(const f32x4*)(p1 + 4);
        const float* p2 = Wi1 + (size_t)(g*Hh + j)*Hh + k0;
        wi1a[g] = *(const f32x4*)p2; wi1b[g] = *(const f32x4*)(p2 + 4);
        const float* p3 = Wh1 + (size_t)(g*Hh + j)*Hh + k0;
        wh1a[g] = *(const f32x4*)p3; wh1b[g] = *(const f32x4*)(p3 + 4);
        bb1[g] = bi1[g*Hh + j] + bh1[g*Hh + j];
    }
    // t-invariant attention params (hoisted out of step loop)
    const float* wr = W2w + (size_t)j*Hh + k0;
    const f32x4 w2a = *(const f32x4*)wr, w2d = *(const f32x4*)(wr + 4);
    const float w2bias = W2b[j];
    const f32x4 va = *(const f32x4*)&vw[k0], vd = *(const f32x4*)&vw[k0 + 4];
    const float vbias = vb[0];

    // cell state lives in lane b (b = l < 16)
    float c0r = (l < 16) ? ic[l*Hh + j]           : 0.f;
    float c1r = (l < 16) ? ic[Bb*Hh + l*Hh + j]   : 0.f;

    // XCD-aware batch mapping for phases 2/3: batch sb served by the 4 blocks
    // with bid%8 == sb%8 (all on one XCD) -> per-XCD L2 footprint = 2 batches
    // of encP+encT = 2 MB < 4 MB L2.
    const int sb  = ((bid >> 5) << 3) | (bid & 7);   // batch 0..15
    const int u   = ((bid >> 3) & 3) * 8 + wid;      // 0..31 within batch
    const int se0 = u << 3;                          // 8 score rows
    const int ch0 = u << 4;                          // 16 ctx outputs
    const int msk = (l < 8) ? smask[sb*TEn + se0 + l] : 1;

    // init h double-buffers (parity 0)
    for (int i = bid*512 + tid; i < Bb*Hh; i += NBLK*512) {
        h0b[i] = ih[i];
        h1v[i] = ih[Bb*Hh + i];
    }
    gsync(sy, bid);

    for (int t = 0; t < TDn; ++t) {
        const int p = t & 1;
        const float* h1r = h1v + p*(Bb*Hh);
        float*       h1w = h1v + (p^1)*(Bb*Hh);
        const float* h0r = h0b + p*(Bb*Hh);
        float*       h0w = h0b + (p^1)*(Bb*Hh);

        // prefetch this step's g0e gates (t-only dependent; hides under phases 1-3)
        float ge0 = 0.f, ge1 = 0.f, ge2 = 0.f, ge3 = 0.f;
        if (l < 16) {
            const float* gp = g0e + ((size_t)(t*Bb + l))*(4*Hh) + j;
            ge0 = gp[0]; ge1 = gp[Hh]; ge2 = gp[2*Hh]; ge3 = gp[3*Hh];
        }

        // ================= phase 1: q = h1 @ W2^T + b2 =================
        {
            for (int i = tid*4; i < Bb*Hh; i += 2048)
                *(f32x4*)&lds[swz(i)] = *(const f32x4*)&h1r[i];
            __syncthreads();
            float qv = 0.f;
            #pragma unroll 4
            for (int b = 0; b < Bb; ++b) {
                f32x4 ha = *(const f32x4*)&lds[swz(b*Hh + k0)];
                f32x4 hd = *(const f32x4*)&lds[swz(b*Hh + k0 + 4)];
                float s = dot4(ha, w2a) + dot4(hd, w2d);
                s = wsum(s);
                qv = (l == b) ? s + w2bias : qv;
            }
            if (l < 16) qb[l*Hh + j] = qv;
        }
        gsync(sy, bid);

        // ================= phase 2: scores = tanh(encP + q).v (masked) =================
        {
            f32x4 qa = *(const f32x4*)&qb[sb*Hh + k0];
            f32x4 qd = *(const f32x4*)&qb[sb*Hh + k0 + 4];
            float myS = 0.f;
            #pragma unroll
            for (int i = 0; i < 8; ++i) {
                const int e = se0 + i;
                const float* ep = encP + ((size_t)(sb*TEn + e))*Hh + k0;
                f32x4 ea = *(const f32x4*)ep, ed = *(const f32x4*)(ep + 4);
                float s = 0.f;
                #pragma unroll
                for (int c = 0; c < 4; ++c)
                    s += tanhfast(ea[c] + qa[c]) * va[c] + tanhfast(ed[c] + qd[c]) * vd[c];
                s = wsum(s);
                myS = (l == i) ? s : myS;
            }
            if (l < 8)
                sc[sb*TEn + se0 + l] = (msk == 0) ? -1e9f : (myS + vbias);
        }
        gsync(sy, bid);

        // ================= phase 3: softmax + context =================
        {
            f32x4 s4 = *(const f32x4*)&sc[sb*TEn + (l << 2)];
            float mx = wmax(fmaxf(fmaxf(s4[0], s4[1]), fmaxf(s4[2], s4[3])));
            f32x4 e4; float sm = 0.f;
            #pragma unroll
            for (int c = 0; c < 4; ++c) { e4[c] = __expf(s4[c] - mx); sm += e4[c]; }
            sm = wsum(sm);
            const float inv = 1.0f / sm;
            float myC = 0.f;
            #pragma unroll 4
            for (int i = 0; i < 16; ++i) {
                const int h = ch0 + i;
                f32x4 en = *(const f32x4*)&encT[((size_t)(sb*Hh + h))*TEn + (l << 2)];
                float s = wsum(dot4(e4, en));
                myC = (l == i) ? s : myC;
            }
            if (l < 16) ctx[sb*Hh + ch0 + l] = myC * inv;
        }
        gsync(sy, bid);

        // ================= phase 4: LSTM layer 0 =================
        {
            for (int i = tid*4; i < Bb*Hh; i += 2048) {
                *(f32x4*)&lds[swz(i)]          = *(const f32x4*)&ctx[i];
                *(f32x4*)&lds[swz(Bb*Hh + i)]  = *(const f32x4*)&h0r[i];
            }
            __syncthreads();
            float ls0 = 0.f, ls1 = 0.f, ls2 = 0.f, ls3 = 0.f;
            #pragma unroll 4
            for (int b = 0; b < Bb; ++b) {
                f32x4 xa = *(const f32x4*)&lds[swz(b*Hh + k0)];
                f32x4 xd = *(const f32x4*)&lds[swz(b*Hh + k0 + 4)];
                f32x4 ha = *(const f32x4*)&lds[swz(Bb*Hh + b*Hh + k0)];
                f32x4 hd = *(const f32x4*)&lds[swz(Bb*Hh + b*Hh + k0 + 4)];
                float s0 = dot4(wi0a[0],xa)+dot4(wi0b[0],xd)+dot4(wh0a[0],ha)+dot4(wh0b[0],hd);
                float s1 = dot4(wi0a[1],xa)+dot4(wi0b[1],xd)+dot4(wh0a[1],ha)+dot4(wh0b[1],hd);
                float s2 = dot4(wi0a[2],xa)+dot4(wi0b[2],xd)+dot4(wh0a[2],ha)+dot4(wh0b[2],hd);
                float s3 = dot4(wi0a[3],xa)+dot4(wi0b[3],xd)+dot4(wh0a[3],ha)+dot4(wh0b[3],hd);
                wsum4(s0, s1, s2, s3);
                if (l == b) { ls0 = s0; ls1 = s1; ls2 = s2; ls3 = s3; }
            }
            if (l < 16) {
                float ii = sigm(ls0 + ge0), ff = sigm(ls1 + ge1);
                float gg = tanhfast(ls2 + ge2), oo = sigm(ls3 + ge3);
                float cn = ff*c0r + ii*gg;
                c0r = cn;
                h0w[l*Hh + j] = oo * tanhfast(cn);
            }
        }
        gsync(sy, bid);

        // ================= phase 5: LSTM layer 1 + bf16 h1 store =================
        {
            for (int i = tid*4; i < Bb*Hh; i += 2048) {
                *(f32x4*)&lds[swz(i)]          = *(const f32x4*)&h0w[i];
                *(f32x4*)&lds[swz(Bb*Hh + i)]  = *(const f32x4*)&h1r[i];
            }
            __syncthreads();
            float ls0 = 0.f, ls1 = 0.f, ls2 = 0.f, ls3 = 0.f;
            #pragma unroll 4
            for (int b = 0; b < Bb; ++b) {
                f32x4 xa = *(const f32x4*)&lds[swz(b*Hh + k0)];
                f32x4 xd = *(const f32x4*)&lds[swz(b*Hh + k0 + 4)];
                f32x4 ha = *(const f32x4*)&lds[swz(Bb*Hh + b*Hh + k0)];
                f32x4 hd = *(const f32x4*)&lds[swz(Bb*Hh + b*Hh + k0 + 4)];
                float s0 = dot4(wi1a[0],xa)+dot4(wi1b[0],xd)+dot4(wh1a[0],ha)+dot4(wh1b[0],hd);
                float s1 = dot4(wi1a[1],xa)+dot4(wi1b[1],xd)+dot4(wh1a[1],ha)+dot4(wh1b[1],hd);
                float s2 = dot4(wi1a[2],xa)+dot4(wi1b[2],xd)+dot4(wh1a[2],ha)+dot4(wh1b[2],hd);
                float s3 = dot4(wi1a[3],xa)+dot4(wi1b[3],xd)+dot4(wh1a[3],ha)+dot4(wh1b[3],hd);
                wsum4(s0, s1, s2, s3);
                if (l == b) { ls0 = s0; ls1 = s1; ls2 = s2; ls3 = s3; }
            }
            if (l < 16) {
                float ii = sigm(ls0 + bb1[0]), ff = sigm(ls1 + bb1[1]);
                float gg = tanhfast(ls2 + bb1[2]), oo = sigm(ls3 + bb1[3]);
                float cn = ff*c1r + ii*gg;
                c1r = cn;
                float hn = oo * tanhfast(cn);
                h1w[l*Hh + j] = hn;
                h1bf[((size_t)(t*Bb + l))*Hh + j] = f2bf(hn);
            }
        }
        gsync(sy, bid);
    }
}

extern "C" void kernel_launch(void* const* d_in, const int* in_sizes, int n_in,
                              void* d_out, int out_size, void* d_ws, size_t ws_size,
                              hipStream_t stream)
{
    const int*   ids  = (const int*)d_in[0];
    const float* ih   = (const float*)d_in[1];
    const float* ic   = (const float*)d_in[2];
    const float* enc  = (const float*)d_in[3];
    const int*   smask= (const int*)d_in[4];
    const float* emb  = (const float*)d_in[5];
    const float* W1w  = (const float*)d_in[6];
    const float* W1b  = (const float*)d_in[7];
    const float* W2w  = (const float*)d_in[8];
    const float* W2b  = (const float*)d_in[9];
    const float* vw   = (const float*)d_in[10];
    const float* vb   = (const float*)d_in[11];
    const float* Wi0  = (const float*)d_in[12];
    const float* Wh0  = (const float*)d_in[13];
    const float* bi0  = (const float*)d_in[14];
    const float* bh0  = (const float*)d_in[15];
    const float* Wi1  = (const float*)d_in[16];
    const float* Wh1  = (const float*)d_in[17];
    const float* bi1  = (const float*)d_in[18];
    const float* bh1  = (const float*)d_in[19];
    const float* fcw  = (const float*)d_in[20];
    const float* fcb  = (const float*)d_in[21];
    float* out = (float*)d_out;
    char*  ws  = (char*)d_ws;

    // barrier counters must start at 0 (ws is poisoned 0xAA before timing)
    hipMemsetAsync(ws + OFF_SYNC, 0, 2048, stream);

    // prep: fc_w -> bf16 (padded)
    prep_fcw_kernel<<<dim3((unsigned)((size_t)NPAD*Hh/8/256)), dim3(256), 0, stream>>>(
        fcw, (unsigned short*)(ws + OFF_FCWB));

    // prep: enc transpose
    transpose_kernel<<<dim3(TEn/32, Hh/32, Bb), dim3(32, 8), 0, stream>>>(
        enc, (float*)(ws + OFF_ENCT));

    // enc_proj = enc @ W1^T + b1
    gemm_bt<0,0,0><<<dim3(Hh/128, (Bb*TEn)/128), dim3(256), 0, stream>>>(
        enc, W1w, W1b, nullptr, (float*)(ws + OFF_ENCP),
        Bb*TEn, Hh, Hh, Hh, nullptr, 0);

    // g0_emb = emb[ids] @ W_ih0[:, :E]^T + b_ih0 + b_hh0
    gemm_bt<0,1,0><<<dim3((4*Hh)/128, (TDn*Bb)/128), dim3(256), 0, stream>>>(
        emb, Wi0, bi0, bh0, (float*)(ws + OFF_G0E),
        TDn*Bb, 4*Hh, Ee, Ee + Hh, ids, 0);

    // sequential recurrence (cooperative, 64 blocks x 512 threads)
    {
        void* args[] = { (void*)&ih, (void*)&ic, (void*)&W2w, (void*)&W2b,
                         (void*)&vw, (void*)&vb, (void*)&smask,
                         (void*)&Wi0, (void*)&Wh0, (void*)&Wi1, (void*)&Wh1,
                         (void*)&bi1, (void*)&bh1, (void*)&ws };
        hipLaunchCooperativeKernel((void*)recur_kernel, dim3(NBLK), dim3(512), args, 0, stream);
    }

    // logits = h1_all @ fc_w^T + fc_b   (batched over all 64 steps)
    gemm_bt<1,0,1><<<dim3(NPAD/128, (TDn*Bb)/128), dim3(256), 0, stream>>>(
        ws + OFF_H1B, ws + OFF_FCWB, fcb, nullptr, out,
        TDn*Bb, NPAD, Hh, Hh, nullptr, Vv);
}

// Round 4
// 3747.651 us; speedup vs baseline: 2.5139x; 1.3042x over previous
//
#include <hip/hip_runtime.h>

#define DI __device__ __forceinline__

typedef __attribute__((ext_vector_type(2))) float f32x2;
typedef __attribute__((ext_vector_type(4))) float f32x4;
typedef __attribute__((ext_vector_type(8))) short bf16x8;
typedef __attribute__((ext_vector_type(8))) unsigned short u16x8;

constexpr int Vv = 50257, NPAD = 50304, Ee = 512, Hh = 512, Bb = 16, TDn = 64, TEn = 256;
constexpr int NBLK = 64;   // recurrence blocks (8 per XCD), 512 thr each -> 512 waves

// ---- workspace layout (bytes) ----
constexpr size_t OFF_ENCP = 0;                                          // (B*TE, H) f32
constexpr size_t OFF_ENCT = OFF_ENCP + (size_t)Bb*TEn*Hh*4;             // (B, H, TE) f32
constexpr size_t OFF_G0E  = OFF_ENCT + (size_t)Bb*Hh*TEn*4;             // (TD*B, 4H) f32
constexpr size_t OFF_FCWB = OFF_G0E  + (size_t)TDn*Bb*4*Hh*4;           // (NPAD, H) bf16
constexpr size_t OFF_H1B  = OFF_FCWB + (size_t)NPAD*Hh*2;               // (TD*B, H) bf16
constexpr size_t OFF_Q    = OFF_H1B  + (size_t)TDn*Bb*Hh*2;             // (B, H) f32
constexpr size_t OFF_SC   = OFF_Q    + (size_t)Bb*Hh*4;                 // (B, TE) f32
constexpr size_t OFF_CTX  = OFF_SC   + (size_t)Bb*TEn*4;                // (B, H) f32
constexpr size_t OFF_H0   = OFF_CTX  + (size_t)Bb*Hh*4;                 // 2x (B,H)
constexpr size_t OFF_H1   = OFF_H0   + (size_t)2*Bb*Hh*4;               // 2x (B,H)
constexpr size_t OFF_SYNC = OFF_H1   + (size_t)2*Bb*Hh*4;               // 2 KiB sync area

DI float dot4(f32x4 a, f32x4 b) { return a[0]*b[0] + a[1]*b[1] + a[2]*b[2] + a[3]*b[3]; }
DI float wsum(float v) { for (int m = 32; m; m >>= 1) v += __shfl_xor(v, m, 64); return v; }
DI float wmax(float v) { for (int m = 32; m; m >>= 1) v = fmaxf(v, __shfl_xor(v, m, 64)); return v; }
DI void wsum4(float& a, float& b, float& c, float& d) {
    #pragma unroll
    for (int m = 32; m; m >>= 1) {
        a += __shfl_xor(a, m, 64);
        b += __shfl_xor(b, m, 64);
        c += __shfl_xor(c, m, 64);
        d += __shfl_xor(d, m, 64);
    }
}
DI float tanhfast(float x) { float e = __expf(2.f * x); return 1.f - 2.f / (e + 1.f); }
DI float sigm(float x) { return 1.f / (1.f + __expf(-x)); }

// LDS bank-quad spreading swizzle (dword index, preserves 16B blocks)
DI int swz(int a) { return a ^ (((a >> 5) & 7) << 2); }

// ---- agent-scope (device-coherent, L2-bypassing) data path for cross-block state ----
DI float gload1(const float* p) {
    return __hip_atomic_load(p, __ATOMIC_RELAXED, __HIP_MEMORY_SCOPE_AGENT);
}
DI void gstore1(float* p, float v) {
    __hip_atomic_store(p, v, __ATOMIC_RELAXED, __HIP_MEMORY_SCOPE_AGENT);
}
DI f32x2 gload2(const float* p) {
    unsigned long long u = __hip_atomic_load((const unsigned long long*)p,
                                             __ATOMIC_RELAXED, __HIP_MEMORY_SCOPE_AGENT);
    return __builtin_bit_cast(f32x2, u);
}
DI void gstore2(float* p, f32x2 v) {
    __hip_atomic_store((unsigned long long*)p, __builtin_bit_cast(unsigned long long, v),
                       __ATOMIC_RELAXED, __HIP_MEMORY_SCOPE_AGENT);
}
DI f32x4 gload4(const float* p) {
    f32x2 a = gload2(p), b = gload2(p + 2);
    f32x4 r; r[0] = a[0]; r[1] = a[1]; r[2] = b[0]; r[3] = b[1];
    return r;
}
DI void gstoreu16(unsigned short* p, unsigned short v) {
    __hip_atomic_store(p, v, __ATOMIC_RELAXED, __HIP_MEMORY_SCOPE_AGENT);
}

DI unsigned short f2bf(float f) {
    unsigned u = __builtin_bit_cast(unsigned, f);
    unsigned r = (u + 0x7FFFu + ((u >> 16) & 1u)) >> 16;
    return (unsigned short)r;
}
DI u16x8 cvt8(f32x4 a, f32x4 b) {
    u16x8 r;
    r[0]=f2bf(a[0]); r[1]=f2bf(a[1]); r[2]=f2bf(a[2]); r[3]=f2bf(a[3]);
    r[4]=f2bf(b[0]); r[5]=f2bf(b[1]); r[6]=f2bf(b[2]); r[7]=f2bf(b[3]);
    return r;
}

// ---- fence-free grid barrier: monotonic counter + generation word, relaxed polling ----
// cnt @ sy+0, gen @ sy+64 (256B apart). No buffer_wbl2/buffer_inv in the hot path:
// all cross-block data moves via agent-scope atomics (coherence point), so no L2
// maintenance is needed. Acquire fallback every 1024 spins guards against hangs.
DI void gsync(unsigned* cnt, unsigned* gen, unsigned k) {
    __syncthreads();
    if (threadIdx.x == 0) {
        asm volatile("s_waitcnt vmcnt(0)" ::: "memory");
        unsigned old = __hip_atomic_fetch_add(cnt, 1u, __ATOMIC_RELAXED, __HIP_MEMORY_SCOPE_AGENT);
        if (old == k * (unsigned)NBLK - 1u) {
            __hip_atomic_store(gen, k, __ATOMIC_RELAXED, __HIP_MEMORY_SCOPE_AGENT);
        } else {
            int spins = 0;
            while (true) {
                unsigned g = __hip_atomic_load(gen, __ATOMIC_RELAXED, __HIP_MEMORY_SCOPE_AGENT);
                if (g >= k) break;
                __builtin_amdgcn_s_sleep(1);
                if ((++spins & 1023) == 0) {
                    g = __hip_atomic_load(gen, __ATOMIC_ACQUIRE, __HIP_MEMORY_SCOPE_AGENT);
                    if (g >= k) break;
                }
            }
        }
        asm volatile("" ::: "memory");
    }
    __syncthreads();
}

// ---- prep: fc_w f32 -> bf16, padded to NPAD rows ----
__global__ void prep_fcw_kernel(const float* __restrict__ src, unsigned short* __restrict__ dst) {
    size_t i = ((size_t)blockIdx.x * 256 + threadIdx.x) << 3;
    int n = (int)(i >> 9);
    u16x8 v = {0,0,0,0,0,0,0,0};
    if (n < Vv) {
        const float* p = src + i;
        v = cvt8(*(const f32x4*)p, *(const f32x4*)(p + 4));
    }
    *(u16x8*)(dst + i) = v;
}

// ---- prep: enc (B,TE,H) -> encT (B,H,TE) ----
__global__ void transpose_kernel(const float* __restrict__ enc, float* __restrict__ encT) {
    __shared__ float tile[32][33];
    const int b = blockIdx.z, e0 = blockIdx.x << 5, h0 = blockIdx.y << 5;
    const int tx = threadIdx.x, ty = threadIdx.y;  // 32 x 8
    #pragma unroll
    for (int i = 0; i < 4; ++i)
        tile[ty + i*8][tx] = enc[((size_t)(b*TEn + e0 + ty + i*8))*Hh + h0 + tx];
    __syncthreads();
    #pragma unroll
    for (int i = 0; i < 4; ++i)
        encT[((size_t)(b*Hh + h0 + ty + i*8))*TEn + e0 + tx] = tile[tx][ty + i*8];
}

// ---- MFMA bf16 GEMM: C[m][n] = sum_k A[m][k]*B[n][k] (+bias), 128x128x32 tiles ----
template<int SRCBF, int GATHER, int OUTM>
__global__ __launch_bounds__(256, 2) void gemm_bt(
    const void* __restrict__ Av, const void* __restrict__ Bv,
    const float* __restrict__ bias, const float* __restrict__ bias2,
    float* __restrict__ Cout, int M, int N, int K, int ldb,
    const int* __restrict__ ids, int NV)
{
    __shared__ unsigned short As[128*32], Bs[128*32];
    const int tid = threadIdx.x;
    const int bn = blockIdx.x, bm = blockIdx.y;
    const int w = tid >> 6, l = tid & 63;
    const int wm = w >> 1, wn = w & 1;
    const int lr = l & 15, ls = l >> 4;
    f32x4 acc[4][4] = {};

    const int r0 = tid >> 2, c0 = (tid & 3) << 3;

    for (int kb = 0; kb < K; kb += 32) {
        #pragma unroll
        for (int half = 0; half < 2; ++half) {
            const int rr = r0 + half*64;
            {   // A tile
                const int gm = bm*128 + rr;
                size_t arow = GATHER ? (size_t)ids[((gm & 15) << 6) + (gm >> 4)] : (size_t)gm;
                u16x8 v;
                if (SRCBF) {
                    v = *(const u16x8*)((const unsigned short*)Av + arow*(size_t)K + kb + c0);
                } else {
                    const float* ap = (const float*)Av + arow*(size_t)K + kb + c0;
                    v = cvt8(*(const f32x4*)ap, *(const f32x4*)(ap + 4));
                }
                *(u16x8*)&As[rr*32 + c0] = v;
            }
            {   // B tile
                const size_t brow = (size_t)(bn*128 + rr);
                u16x8 v;
                if (SRCBF) {
                    v = *(const u16x8*)((const unsigned short*)Bv + brow*(size_t)ldb + kb + c0);
                } else {
                    const float* bp = (const float*)Bv + brow*(size_t)ldb + kb + c0;
                    v = cvt8(*(const f32x4*)bp, *(const f32x4*)(bp + 4));
                }
                *(u16x8*)&Bs[rr*32 + c0] = v;
            }
        }
        __syncthreads();
        bf16x8 af[4], bfv[4];
        #pragma unroll
        for (int mt = 0; mt < 4; ++mt) af[mt]  = *(const bf16x8*)&As[(wm*64 + mt*16 + lr)*32 + ls*8];
        #pragma unroll
        for (int nt = 0; nt < 4; ++nt) bfv[nt] = *(const bf16x8*)&Bs[(wn*64 + nt*16 + lr)*32 + ls*8];
        #pragma unroll
        for (int mt = 0; mt < 4; ++mt)
            #pragma unroll
            for (int nt = 0; nt < 4; ++nt)
                acc[mt][nt] = __builtin_amdgcn_mfma_f32_16x16x32_bf16(af[mt], bfv[nt], acc[mt][nt], 0, 0, 0);
        __syncthreads();
    }

    #pragma unroll
    for (int mt = 0; mt < 4; ++mt) {
        #pragma unroll
        for (int nt = 0; nt < 4; ++nt) {
            const int n = bn*128 + wn*64 + nt*16 + lr;
            const int mbase = bm*128 + wm*64 + mt*16 + ls*4;
            f32x4 a = acc[mt][nt];
            #pragma unroll
            for (int r = 0; r < 4; ++r) {
                const int m = mbase + r;
                if (OUTM == 0) {
                    float v = a[r] + bias[n] + (bias2 ? bias2[n] : 0.f);
                    Cout[(size_t)m*N + n] = v;
                } else {
                    if (n < NV) {
                        float v = a[r] + bias[n];
                        Cout[(size_t)(((m & 15) << 6) + (m >> 4))*NV + n] = v;
                    }
                }
            }
        }
    }
}

// ---- cooperative recurrence: 64 blocks x 512 thr; wave j owns gate-row j; weights in VGPRs ----
__global__ __launch_bounds__(512, 1) void recur_kernel(
    const float* __restrict__ ih, const float* __restrict__ ic,
    const float* __restrict__ W2w, const float* __restrict__ W2b,
    const float* __restrict__ vw, const float* __restrict__ vb,
    const int* __restrict__ smask,
    const float* __restrict__ Wi0, const float* __restrict__ Wh0,
    const float* __restrict__ Wi1, const float* __restrict__ Wh1,
    const float* __restrict__ bi1, const float* __restrict__ bh1,
    char* __restrict__ ws)
{
    float* encP = (float*)(ws + OFF_ENCP);
    float* encT = (float*)(ws + OFF_ENCT);
    float* g0e  = (float*)(ws + OFF_G0E);
    unsigned short* h1bf = (unsigned short*)(ws + OFF_H1B);
    float* qb  = (float*)(ws + OFF_Q);
    float* sc  = (float*)(ws + OFF_SC);
    float* ctx = (float*)(ws + OFF_CTX);
    float* h0b = (float*)(ws + OFF_H0);
    float* h1v = (float*)(ws + OFF_H1);
    unsigned* cnt = (unsigned*)(ws + OFF_SYNC);
    unsigned* gen = cnt + 64;   // 256B apart

    __shared__ float lds[2 * Bb * Hh];   // 64 KiB staging

    const int tid = threadIdx.x, bid = blockIdx.x;
    const int wid = tid >> 6, l = tid & 63;
    const int j  = (bid << 3) + wid;     // owned column / global wave id, 0..511
    const int k0 = l << 3;               // lane k-slice (8 floats)

    // ---- persistent per-lane LSTM weight fragments (128 VGPRs) ----
    f32x4 wi0a[4], wi0b[4], wh0a[4], wh0b[4];
    f32x4 wi1a[4], wi1b[4], wh1a[4], wh1b[4];
    float bb1[4];
    #pragma unroll
    for (int g = 0; g < 4; ++g) {
        const float* p0 = Wi0 + (size_t)(g*Hh + j)*(Ee + Hh) + Ee + k0;
        wi0a[g] = *(const f32x4*)p0; wi0b[g] = *(const f32x4*)(p0 + 4);
        const float* p1 = Wh0 + (size_t)(g*Hh + j)*Hh + k0;
        wh0a[g] = *(const f32x4*)p1; wh0b[g] = *(const f32x4*)(p1 + 4);
        const float* p2 = Wi1 + (size_t)(g*Hh + j)*Hh + k0;
        wi1a[g] = *(const f32x4*)p2; wi1b[g] = *(const f32x4*)(p2 + 4);
        const float* p3 = Wh1 + (size_t)(g*Hh + j)*Hh + k0;
        wh1a[g] = *(const f32x4*)p3; wh1b[g] = *(const f32x4*)(p3 + 4);
        bb1[g] = bi1[g*Hh + j] + bh1[g*Hh + j];
    }
    // t-invariant attention params (hoisted out of step loop)
    const float* wr = W2w + (size_t)j*Hh + k0;
    const f32x4 w2a = *(const f32x4*)wr, w2d = *(const f32x4*)(wr + 4);
    const float w2bias = W2b[j];
    const f32x4 va = *(const f32x4*)&vw[k0], vd = *(const f32x4*)&vw[k0 + 4];
    const float vbias = vb[0];

    // cell state lives in lane b (b = l < 16)
    float c0r = (l < 16) ? ic[l*Hh + j]           : 0.f;
    float c1r = (l < 16) ? ic[Bb*Hh + l*Hh + j]   : 0.f;

    // XCD-aware batch mapping for phases 2/3 (keeps encP/encT slices XCD-L2-resident,
    // which now pays off since the barrier no longer invalidates L2)
    const int sb  = ((bid >> 5) << 3) | (bid & 7);   // batch 0..15
    const int u   = ((bid >> 3) & 3) * 8 + wid;      // 0..31 within batch
    const int se0 = u << 3;                          // 8 score rows
    const int ch0 = u << 4;                          // 16 ctx outputs
    const int msk = (l < 8) ? smask[sb*TEn + se0 + l] : 1;

    // init h double-buffers (parity 0) via coherent stores
    for (int i = bid*512 + tid; i < (Bb*Hh) / 2; i += NBLK*512) {
        gstore2(&h0b[i*2], *(const f32x2*)&ih[i*2]);
        gstore2(&h1v[i*2], *(const f32x2*)&ih[Bb*Hh + i*2]);
    }
    unsigned bk = 0;
    gsync(cnt, gen, ++bk);

    for (int t = 0; t < TDn; ++t) {
        const int p = t & 1;
        const float* h1r = h1v + p*(Bb*Hh);
        float*       h1w = h1v + (p^1)*(Bb*Hh);
        const float* h0r = h0b + p*(Bb*Hh);
        float*       h0w = h0b + (p^1)*(Bb*Hh);

        // prefetch this step's g0e gates (plain cached loads; written pre-kernel)
        float ge0 = 0.f, ge1 = 0.f, ge2 = 0.f, ge3 = 0.f;
        if (l < 16) {
            const float* gp = g0e + ((size_t)(t*Bb + l))*(4*Hh) + j;
            ge0 = gp[0]; ge1 = gp[Hh]; ge2 = gp[2*Hh]; ge3 = gp[3*Hh];
        }

        // ================= phase 1: q = h1 @ W2^T + b2 =================
        {
            for (int i = tid*2; i < Bb*Hh; i += 1024)
                *(f32x2*)&lds[swz(i)] = gload2(&h1r[i]);
            __syncthreads();
            float qv = 0.f;
            #pragma unroll 4
            for (int b = 0; b < Bb; ++b) {
                f32x4 ha = *(const f32x4*)&lds[swz(b*Hh + k0)];
                f32x4 hd = *(const f32x4*)&lds[swz(b*Hh + k0 + 4)];
                float s = dot4(ha, w2a) + dot4(hd, w2d);
                s = wsum(s);
                qv = (l == b) ? s + w2bias : qv;
            }
            if (l < 16) gstore1(&qb[l*Hh + j], qv);
        }
        gsync(cnt, gen, ++bk);

        // ================= phase 2: scores = tanh(encP + q).v (masked) =================
        {
            f32x4 qa = gload4(&qb[sb*Hh + k0]);
            f32x4 qd = gload4(&qb[sb*Hh + k0 + 4]);
            float myS = 0.f;
            #pragma unroll
            for (int i = 0; i < 8; ++i) {
                const int e = se0 + i;
                const float* ep = encP + ((size_t)(sb*TEn + e))*Hh + k0;
                f32x4 ea = *(const f32x4*)ep, ed = *(const f32x4*)(ep + 4);
                float s = 0.f;
                #pragma unroll
                for (int c = 0; c < 4; ++c)
                    s += tanhfast(ea[c] + qa[c]) * va[c] + tanhfast(ed[c] + qd[c]) * vd[c];
                s = wsum(s);
                myS = (l == i) ? s : myS;
            }
            if (l < 8)
                gstore1(&sc[sb*TEn + se0 + l], (msk == 0) ? -1e9f : (myS + vbias));
        }
        gsync(cnt, gen, ++bk);

        // ================= phase 3: softmax + context =================
        {
            f32x4 s4 = gload4(&sc[sb*TEn + (l << 2)]);
            float mx = wmax(fmaxf(fmaxf(s4[0], s4[1]), fmaxf(s4[2], s4[3])));
            f32x4 e4; float sm = 0.f;
            #pragma unroll
            for (int c = 0; c < 4; ++c) { e4[c] = __expf(s4[c] - mx); sm += e4[c]; }
            sm = wsum(sm);
            const float inv = 1.0f / sm;
            float myC = 0.f;
            #pragma unroll 4
            for (int i = 0; i < 16; ++i) {
                const int h = ch0 + i;
                f32x4 en = *(const f32x4*)&encT[((size_t)(sb*Hh + h))*TEn + (l << 2)];
                float s = wsum(dot4(e4, en));
                myC = (l == i) ? s : myC;
            }
            if (l < 16) gstore1(&ctx[sb*Hh + ch0 + l], myC * inv);
        }
        gsync(cnt, gen, ++bk);

        // ================= phase 4: LSTM layer 0 =================
        {
            for (int i = tid*2; i < Bb*Hh; i += 1024) {
                *(f32x2*)&lds[swz(i)]          = gload2(&ctx[i]);
                *(f32x2*)&lds[swz(Bb*Hh + i)]  = gload2(&h0r[i]);
            }
            __syncthreads();
            float ls0 = 0.f, ls1 = 0.f, ls2 = 0.f, ls3 = 0.f;
            #pragma unroll 4
            for (int b = 0; b < Bb; ++b) {
                f32x4 xa = *(const f32x4*)&lds[swz(b*Hh + k0)];
                f32x4 xd = *(const f32x4*)&lds[swz(b*Hh + k0 + 4)];
                f32x4 ha = *(const f32x4*)&lds[swz(Bb*Hh + b*Hh + k0)];
                f32x4 hd = *(const f32x4*)&lds[swz(Bb*Hh + b*Hh + k0 + 4)];
                float s0 = dot4(wi0a[0],xa)+dot4(wi0b[0],xd)+dot4(wh0a[0],ha)+dot4(wh0b[0],hd);
                float s1 = dot4(wi0a[1],xa)+dot4(wi0b[1],xd)+dot4(wh0a[1],ha)+dot4(wh0b[1],hd);
                float s2 = dot4(wi0a[2],xa)+dot4(wi0b[2],xd)+dot4(wh0a[2],ha)+dot4(wh0b[2],hd);
                float s3 = dot4(wi0a[3],xa)+dot4(wi0b[3],xd)+dot4(wh0a[3],ha)+dot4(wh0b[3],hd);
                wsum4(s0, s1, s2, s3);
                if (l == b) { ls0 = s0; ls1 = s1; ls2 = s2; ls3 = s3; }
            }
            if (l < 16) {
                float ii = sigm(ls0 + ge0), ff = sigm(ls1 + ge1);
                float gg = tanhfast(ls2 + ge2), oo = sigm(ls3 + ge3);
                float cn = ff*c0r + ii*gg;
                c0r = cn;
                gstore1(&h0w[l*Hh + j], oo * tanhfast(cn));
            }
        }
        gsync(cnt, gen, ++bk);

        // ================= phase 5: LSTM layer 1 + bf16 h1 store =================
        {
            for (int i = tid*2; i < Bb*Hh; i += 1024) {
                *(f32x2*)&lds[swz(i)]          = gload2(&h0w[i]);
                *(f32x2*)&lds[swz(Bb*Hh + i)]  = gload2(&h1r[i]);
            }
            __syncthreads();
            float ls0 = 0.f, ls1 = 0.f, ls2 = 0.f, ls3 = 0.f;
            #pragma unroll 4
            for (int b = 0; b < Bb; ++b) {
                f32x4 xa = *(const f32x4*)&lds[swz(b*Hh + k0)];
                f32x4 xd = *(const f32x4*)&lds[swz(b*Hh + k0 + 4)];
                f32x4 ha = *(const f32x4*)&lds[swz(Bb*Hh + b*Hh + k0)];
                f32x4 hd = *(const f32x4*)&lds[swz(Bb*Hh + b*Hh + k0 + 4)];
                float s0 = dot4(wi1a[0],xa)+dot4(wi1b[0],xd)+dot4(wh1a[0],ha)+dot4(wh1b[0],hd);
                float s1 = dot4(wi1a[1],xa)+dot4(wi1b[1],xd)+dot4(wh1a[1],ha)+dot4(wh1b[1],hd);
                float s2 = dot4(wi1a[2],xa)+dot4(wi1b[2],xd)+dot4(wh1a[2],ha)+dot4(wh1b[2],hd);
                float s3 = dot4(wi1a[3],xa)+dot4(wi1b[3],xd)+dot4(wh1a[3],ha)+dot4(wh1b[3],hd);
                wsum4(s0, s1, s2, s3);
                if (l == b) { ls0 = s0; ls1 = s1; ls2 = s2; ls3 = s3; }
            }
            if (l < 16) {
                float ii = sigm(ls0 + bb1[0]), ff = sigm(ls1 + bb1[1]);
                float gg = tanhfast(ls2 + bb1[2]), oo = sigm(ls3 + bb1[3]);
                float cn = ff*c1r + ii*gg;
                c1r = cn;
                float hn = oo * tanhfast(cn);
                gstore1(&h1w[l*Hh + j], hn);
                gstoreu16(&h1bf[((size_t)(t*Bb + l))*Hh + j], f2bf(hn));
            }
        }
        gsync(cnt, gen, ++bk);
    }
}

extern "C" void kernel_launch(void* const* d_in, const int* in_sizes, int n_in,
                              void* d_out, int out_size, void* d_ws, size_t ws_size,
                              hipStream_t stream)
{
    const int*   ids  = (const int*)d_in[0];
    const float* ih   = (const float*)d_in[1];
    const float* ic   = (const float*)d_in[2];
    const float* enc  = (const float*)d_in[3];
    const int*   smask= (const int*)d_in[4];
    const float* emb  = (const float*)d_in[5];
    const float* W1w  = (const float*)d_in[6];
    const float* W1b  = (const float*)d_in[7];
    const float* W2w  = (const float*)d_in[8];
    const float* W2b  = (const float*)d_in[9];
    const float* vw   = (const float*)d_in[10];
    const float* vb   = (const float*)d_in[11];
    const float* Wi0  = (const float*)d_in[12];
    const float* Wh0  = (const float*)d_in[13];
    const float* bi0  = (const float*)d_in[14];
    const float* bh0  = (const float*)d_in[15];
    const float* Wi1  = (const float*)d_in[16];
    const float* Wh1  = (const float*)d_in[17];
    const float* bi1  = (const float*)d_in[18];
    const float* bh1  = (const float*)d_in[19];
    const float* fcw  = (const float*)d_in[20];
    const float* fcb  = (const float*)d_in[21];
    float* out = (float*)d_out;
    char*  ws  = (char*)d_ws;

    // barrier counters must start at 0 (ws is poisoned 0xAA before timing)
    hipMemsetAsync(ws + OFF_SYNC, 0, 2048, stream);

    // prep: fc_w -> bf16 (padded)
    prep_fcw_kernel<<<dim3((unsigned)((size_t)NPAD*Hh/8/256)), dim3(256), 0, stream>>>(
        fcw, (unsigned short*)(ws + OFF_FCWB));

    // prep: enc transpose
    transpose_kernel<<<dim3(TEn/32, Hh/32, Bb), dim3(32, 8), 0, stream>>>(
        enc, (float*)(ws + OFF_ENCT));

    // enc_proj = enc @ W1^T + b1
    gemm_bt<0,0,0><<<dim3(Hh/128, (Bb*TEn)/128), dim3(256), 0, stream>>>(
        enc, W1w, W1b, nullptr, (float*)(ws + OFF_ENCP),
        Bb*TEn, Hh, Hh, Hh, nullptr, 0);

    // g0_emb = emb[ids] @ W_ih0[:, :E]^T + b_ih0 + b_hh0
    gemm_bt<0,1,0><<<dim3((4*Hh)/128, (TDn*Bb)/128), dim3(256), 0, stream>>>(
        emb, Wi0, bi0, bh0, (float*)(ws + OFF_G0E),
        TDn*Bb, 4*Hh, Ee, Ee + Hh, ids, 0);

    // sequential recurrence (cooperative, 64 blocks x 512 threads)
    {
        void* args[] = { (void*)&ih, (void*)&ic, (void*)&W2w, (void*)&W2b,
                         (void*)&vw, (void*)&vb, (void*)&smask,
                         (void*)&Wi0, (void*)&Wh0, (void*)&Wi1, (void*)&Wh1,
                         (void*)&bi1, (void*)&bh1, (void*)&ws };
        hipLaunchCooperativeKernel((void*)recur_kernel, dim3(NBLK), dim3(512), args, 0, stream);
    }

    // logits = h1_all @ fc_w^T + fc_b   (batched over all 64 steps)
    gemm_bt<1,0,1><<<dim3(NPAD/128, (TDn*Bb)/128), dim3(256), 0, stream>>>(
        ws + OFF_H1B, ws + OFF_FCWB, fcb, nullptr, out,
        TDn*Bb, NPAD, Hh, Hh, nullptr, Vv);
}

// Round 5
// 3362.845 us; speedup vs baseline: 2.8015x; 1.1144x over previous
//
#include <hip/hip_runtime.h>

#define DI __device__ __forceinline__

typedef __attribute__((ext_vector_type(2))) float f32x2;
typedef __attribute__((ext_vector_type(4))) float f32x4;
typedef __attribute__((ext_vector_type(8))) short bf16x8;
typedef __attribute__((ext_vector_type(8))) unsigned short u16x8;

constexpr int Vv = 50257, NPAD = 50304, Ee = 512, Hh = 512, Bb = 16, TDn = 64, TEn = 256;
constexpr int NBLK = 64;   // recurrence blocks, 512 thr each -> 512 waves

// ---- workspace layout (bytes) ----
constexpr size_t OFF_ENCP = 0;                                          // (B*TE, H) f32
constexpr size_t OFF_ENCT = OFF_ENCP + (size_t)Bb*TEn*Hh*4;             // (B, H, TE) f32
constexpr size_t OFF_G0E  = OFF_ENCT + (size_t)Bb*Hh*TEn*4;             // (TD*B, 4H) f32
constexpr size_t OFF_FCWB = OFF_G0E  + (size_t)TDn*Bb*4*Hh*4;           // (NPAD, H) bf16
constexpr size_t OFF_H1B  = OFF_FCWB + (size_t)NPAD*Hh*2;               // (TD*B, H) bf16
constexpr size_t OFF_Q    = OFF_H1B  + (size_t)TDn*Bb*Hh*2;             // (B, H) f32
constexpr size_t OFF_SC   = OFF_Q    + (size_t)Bb*Hh*4;                 // (B, TE) f32
constexpr size_t OFF_CTX  = OFF_SC   + (size_t)Bb*TEn*4;                // (B, H) f32
constexpr size_t OFF_H0   = OFF_CTX  + (size_t)Bb*Hh*4;                 // 2x (B,H)
constexpr size_t OFF_H1   = OFF_H0   + (size_t)2*Bb*Hh*4;               // 2x (B,H)
constexpr size_t OFF_SYNC = OFF_H1   + (size_t)2*Bb*Hh*4;               // 4 KiB sync area
// sync area: gfA@0 (8 u64-lines), gfB@512, grA@1024 (16 u32-lines), grB@2048

DI float dot4(f32x4 a, f32x4 b) { return a[0]*b[0] + a[1]*b[1] + a[2]*b[2] + a[3]*b[3]; }
DI float wsum(float v) { for (int m = 32; m; m >>= 1) v += __shfl_xor(v, m, 64); return v; }
DI float wmax(float v) { for (int m = 32; m; m >>= 1) v = fmaxf(v, __shfl_xor(v, m, 64)); return v; }
DI void wsum4(float& a, float& b, float& c, float& d) {
    #pragma unroll
    for (int m = 32; m; m >>= 1) {
        a += __shfl_xor(a, m, 64);
        b += __shfl_xor(b, m, 64);
        c += __shfl_xor(c, m, 64);
        d += __shfl_xor(d, m, 64);
    }
}
DI float tanhfast(float x) { float e = __expf(2.f * x); return 1.f - 2.f / (e + 1.f); }
DI float sigm(float x) { return 1.f / (1.f + __expf(-x)); }

// LDS bank-quad spreading swizzle (dword index, preserves 16B blocks)
DI int swz(int a) { return a ^ (((a >> 5) & 7) << 2); }

// ---- agent-scope (device-coherent) data path for cross-block state ----
DI float gload1(const float* p) {
    return __hip_atomic_load(p, __ATOMIC_RELAXED, __HIP_MEMORY_SCOPE_AGENT);
}
DI void gstore1(float* p, float v) {
    __hip_atomic_store(p, v, __ATOMIC_RELAXED, __HIP_MEMORY_SCOPE_AGENT);
}
DI f32x2 gload2(const float* p) {
    unsigned long long u = __hip_atomic_load((const unsigned long long*)p,
                                             __ATOMIC_RELAXED, __HIP_MEMORY_SCOPE_AGENT);
    return __builtin_bit_cast(f32x2, u);
}
DI void gstore2(float* p, f32x2 v) {
    __hip_atomic_store((unsigned long long*)p, __builtin_bit_cast(unsigned long long, v),
                       __ATOMIC_RELAXED, __HIP_MEMORY_SCOPE_AGENT);
}
DI f32x4 gload4(const float* p) {
    f32x2 a = gload2(p), b = gload2(p + 2);
    f32x4 r; r[0] = a[0]; r[1] = a[1]; r[2] = b[0]; r[3] = b[1];
    return r;
}
DI void gstoreu16(unsigned short* p, unsigned short v) {
    __hip_atomic_store(p, v, __ATOMIC_RELAXED, __HIP_MEMORY_SCOPE_AGENT);
}

DI unsigned short f2bf(float f) {
    unsigned u = __builtin_bit_cast(unsigned, f);
    unsigned r = (u + 0x7FFFu + ((u >> 16) & 1u)) >> 16;
    return (unsigned short)r;
}
DI u16x8 cvt8(f32x4 a, f32x4 b) {
    u16x8 r;
    r[0]=f2bf(a[0]); r[1]=f2bf(a[1]); r[2]=f2bf(a[2]); r[3]=f2bf(a[3]);
    r[4]=f2bf(b[0]); r[5]=f2bf(b[1]); r[6]=f2bf(b[2]); r[7]=f2bf(b[3]);
    return r;
}

// ---- RMW-free global barrier: per-block byte flags (8 u64 lines), self-detecting.
// Ping-pong arrays by kg parity; skew across blocks is <=1 epoch so byte compare
// (mod 256) is unambiguous. No fetch_add serialization, no release hop.
DI void gbar(char* sy, int bid, unsigned kg) {
    __syncthreads();
    if (threadIdx.x < 64) {
        unsigned long long* gf = (unsigned long long*)(sy + ((kg & 1) ? 0 : 512));
        if (threadIdx.x == 0) {
            asm volatile("s_waitcnt vmcnt(0)" ::: "memory");
            char* p = (char*)(gf + (size_t)(bid >> 3) * 8) + (bid & 7);
            __hip_atomic_store(p, (char)(unsigned char)kg, __ATOMIC_RELAXED, __HIP_MEMORY_SCOPE_AGENT);
        }
        const unsigned long long pat = 0x0101010101010101ULL * (unsigned char)kg;
        const int lane = threadIdx.x;
        for (;;) {
            bool ok = true;
            if (lane < 8)
                ok = (__hip_atomic_load(gf + (size_t)lane * 8, __ATOMIC_RELAXED,
                                        __HIP_MEMORY_SCOPE_AGENT) == pat);
            if (__all(ok)) break;
            __builtin_amdgcn_s_sleep(1);
        }
    }
    __syncthreads();
}

// ---- 4-block group barrier (one u32 word per group), same scheme ----
DI void rbar(char* sy, int g, int u4, unsigned kr) {
    __syncthreads();
    if (threadIdx.x == 0) {
        unsigned* gr = (unsigned*)(sy + ((kr & 1) ? 1024 : 2048));
        asm volatile("s_waitcnt vmcnt(0)" ::: "memory");
        char* p = (char*)(gr + (size_t)g * 16) + u4;
        __hip_atomic_store(p, (char)(unsigned char)kr, __ATOMIC_RELAXED, __HIP_MEMORY_SCOPE_AGENT);
        const unsigned pat = 0x01010101u * (unsigned char)kr;
        while (__hip_atomic_load(gr + (size_t)g * 16, __ATOMIC_RELAXED,
                                 __HIP_MEMORY_SCOPE_AGENT) != pat)
            __builtin_amdgcn_s_sleep(1);
    }
    __syncthreads();
}

// ---- prep: fc_w f32 -> bf16, padded to NPAD rows ----
__global__ void prep_fcw_kernel(const float* __restrict__ src, unsigned short* __restrict__ dst) {
    size_t i = ((size_t)blockIdx.x * 256 + threadIdx.x) << 3;
    int n = (int)(i >> 9);
    u16x8 v = {0,0,0,0,0,0,0,0};
    if (n < Vv) {
        const float* p = src + i;
        v = cvt8(*(const f32x4*)p, *(const f32x4*)(p + 4));
    }
    *(u16x8*)(dst + i) = v;
}

// ---- prep: enc (B,TE,H) -> encT (B,H,TE) ----
__global__ void transpose_kernel(const float* __restrict__ enc, float* __restrict__ encT) {
    __shared__ float tile[32][33];
    const int b = blockIdx.z, e0 = blockIdx.x << 5, h0 = blockIdx.y << 5;
    const int tx = threadIdx.x, ty = threadIdx.y;  // 32 x 8
    #pragma unroll
    for (int i = 0; i < 4; ++i)
        tile[ty + i*8][tx] = enc[((size_t)(b*TEn + e0 + ty + i*8))*Hh + h0 + tx];
    __syncthreads();
    #pragma unroll
    for (int i = 0; i < 4; ++i)
        encT[((size_t)(b*Hh + h0 + ty + i*8))*TEn + e0 + tx] = tile[tx][ty + i*8];
}

// ---- MFMA bf16 GEMM: C[m][n] = sum_k A[m][k]*B[n][k] (+bias), 128x128x32 tiles ----
template<int SRCBF, int GATHER, int OUTM>
__global__ __launch_bounds__(256, 2) void gemm_bt(
    const void* __restrict__ Av, const void* __restrict__ Bv,
    const float* __restrict__ bias, const float* __restrict__ bias2,
    float* __restrict__ Cout, int M, int N, int K, int ldb,
    const int* __restrict__ ids, int NV)
{
    __shared__ unsigned short As[128*32], Bs[128*32];
    const int tid = threadIdx.x;
    const int bn = blockIdx.x, bm = blockIdx.y;
    const int w = tid >> 6, l = tid & 63;
    const int wm = w >> 1, wn = w & 1;
    const int lr = l & 15, ls = l >> 4;
    f32x4 acc[4][4] = {};

    const int r0 = tid >> 2, c0 = (tid & 3) << 3;

    for (int kb = 0; kb < K; kb += 32) {
        #pragma unroll
        for (int half = 0; half < 2; ++half) {
            const int rr = r0 + half*64;
            {   // A tile
                const int gm = bm*128 + rr;
                size_t arow = GATHER ? (size_t)ids[((gm & 15) << 6) + (gm >> 4)] : (size_t)gm;
                u16x8 v;
                if (SRCBF) {
                    v = *(const u16x8*)((const unsigned short*)Av + arow*(size_t)K + kb + c0);
                } else {
                    const float* ap = (const float*)Av + arow*(size_t)K + kb + c0;
                    v = cvt8(*(const f32x4*)ap, *(const f32x4*)(ap + 4));
                }
                *(u16x8*)&As[rr*32 + c0] = v;
            }
            {   // B tile
                const size_t brow = (size_t)(bn*128 + rr);
                u16x8 v;
                if (SRCBF) {
                    v = *(const u16x8*)((const unsigned short*)Bv + brow*(size_t)ldb + kb + c0);
                } else {
                    const float* bp = (const float*)Bv + brow*(size_t)ldb + kb + c0;
                    v = cvt8(*(const f32x4*)bp, *(const f32x4*)(bp + 4));
                }
                *(u16x8*)&Bs[rr*32 + c0] = v;
            }
        }
        __syncthreads();
        bf16x8 af[4], bfv[4];
        #pragma unroll
        for (int mt = 0; mt < 4; ++mt) af[mt]  = *(const bf16x8*)&As[(wm*64 + mt*16 + lr)*32 + ls*8];
        #pragma unroll
        for (int nt = 0; nt < 4; ++nt) bfv[nt] = *(const bf16x8*)&Bs[(wn*64 + nt*16 + lr)*32 + ls*8];
        #pragma unroll
        for (int mt = 0; mt < 4; ++mt)
            #pragma unroll
            for (int nt = 0; nt < 4; ++nt)
                acc[mt][nt] = __builtin_amdgcn_mfma_f32_16x16x32_bf16(af[mt], bfv[nt], acc[mt][nt], 0, 0, 0);
        __syncthreads();
    }

    #pragma unroll
    for (int mt = 0; mt < 4; ++mt) {
        #pragma unroll
        for (int nt = 0; nt < 4; ++nt) {
            const int n = bn*128 + wn*64 + nt*16 + lr;
            const int mbase = bm*128 + wm*64 + mt*16 + ls*4;
            f32x4 a = acc[mt][nt];
            #pragma unroll
            for (int r = 0; r < 4; ++r) {
                const int m = mbase + r;
                if (OUTM == 0) {
                    float v = a[r] + bias[n] + (bias2 ? bias2[n] : 0.f);
                    Cout[(size_t)m*N + n] = v;
                } else {
                    if (n < NV) {
                        float v = a[r] + bias[n];
                        Cout[(size_t)(((m & 15) << 6) + (m >> 4))*NV + n] = v;
                    }
                }
            }
        }
    }
}

// ---- cooperative recurrence: 64 blocks x 512 thr ----
// j-phases (Q, LSTM0, LSTM1): wave j = bid*8+wid owns gate-row j, weights in VGPRs.
// batch-phases (scores, softmax+ctx): group g = bid>>2 owns batch g; u4 = bid&3.
// Schedule/step: Q -G- scores -g- softmax+ctx -G- LSTM0 -G- LSTM1 -G-
__global__ __launch_bounds__(512, 1) void recur_kernel(
    const float* __restrict__ ih, const float* __restrict__ ic,
    const float* __restrict__ W2w, const float* __restrict__ W2b,
    const float* __restrict__ vw, const float* __restrict__ vb,
    const int* __restrict__ smask,
    const float* __restrict__ Wi0, const float* __restrict__ Wh0,
    const float* __restrict__ Wi1, const float* __restrict__ Wh1,
    const float* __restrict__ bi1, const float* __restrict__ bh1,
    char* __restrict__ ws)
{
    float* encP = (float*)(ws + OFF_ENCP);
    float* encT = (float*)(ws + OFF_ENCT);
    float* g0e  = (float*)(ws + OFF_G0E);
    unsigned short* h1bf = (unsigned short*)(ws + OFF_H1B);
    float* qb  = (float*)(ws + OFF_Q);
    float* sc  = (float*)(ws + OFF_SC);
    float* ctx = (float*)(ws + OFF_CTX);
    float* h0b = (float*)(ws + OFF_H0);
    float* h1v = (float*)(ws + OFF_H1);
    char* sy   = (char*)(ws + OFF_SYNC);

    __shared__ float lds[2 * Bb * Hh];   // 64 KiB staging

    const int tid = threadIdx.x, bid = blockIdx.x;
    const int wid = tid >> 6, l = tid & 63;
    const int j  = (bid << 3) + wid;     // owned gate-row, 0..511
    const int k0 = l << 3;               // lane k-slice (8 floats)

    // ---- persistent per-lane LSTM weight fragments ----
    f32x4 wi0a[4], wi0b[4], wh0a[4], wh0b[4];
    f32x4 wi1a[4], wi1b[4], wh1a[4], wh1b[4];
    float bb1[4];
    #pragma unroll
    for (int g = 0; g < 4; ++g) {
        const float* p0 = Wi0 + (size_t)(g*Hh + j)*(Ee + Hh) + Ee + k0;
        wi0a[g] = *(const f32x4*)p0; wi0b[g] = *(const f32x4*)(p0 + 4);
        const float* p1 = Wh0 + (size_t)(g*Hh + j)*Hh + k0;
        wh0a[g] = *(const f32x4*)p1; wh0b[g] = *(const f32x4*)(p1 + 4);
        const float* p2 = Wi1 + (size_t)(g*Hh + j)*Hh + k0;
        wi1a[g] = *(const f32x4*)p2; wi1b[g] = *(const f32x4*)(p2 + 4);
        const float* p3 = Wh1 + (size_t)(g*Hh + j)*Hh + k0;
        wh1a[g] = *(const f32x4*)p3; wh1b[g] = *(const f32x4*)(p3 + 4);
        bb1[g] = bi1[g*Hh + j] + bh1[g*Hh + j];
    }
    // t-invariant attention params
    const float* wr = W2w + (size_t)j*Hh + k0;
    const f32x4 w2a = *(const f32x4*)wr, w2d = *(const f32x4*)(wr + 4);
    const float w2bias = W2b[j];
    const f32x4 va = *(const f32x4*)&vw[k0], vd = *(const f32x4*)&vw[k0 + 4];
    const float vbias = vb[0];

    // cell state lives in lane b (b = l < 16)
    float c0r = (l < 16) ? ic[l*Hh + j]           : 0.f;
    float c1r = (l < 16) ? ic[Bb*Hh + l*Hh + j]   : 0.f;

    // batch-phase mapping: 4 blocks per batch; per-block slices are exclusive ->
    // encP/encT slices stay L2-resident in the owning block's XCD.
    const int gb  = bid >> 2, u4 = bid & 3;
    const int se0 = u4*64 + wid*8;        // 8 score rows per wave
    const int ch0 = u4*128 + wid*16;      // 16 ctx cols per wave
    const int msk = (l < 8) ? smask[gb*TEn + se0 + l] : 1;

    // init h double-buffers (parity 0)
    for (int i = (bid*512 + tid)*4; i < Bb*Hh; i += NBLK*512*4) {
        gstore2(&h0b[i],     *(const f32x2*)&ih[i]);
        gstore2(&h0b[i + 2], *(const f32x2*)&ih[i + 2]);
        gstore2(&h1v[i],     *(const f32x2*)&ih[Bb*Hh + i]);
        gstore2(&h1v[i + 2], *(const f32x2*)&ih[Bb*Hh + i + 2]);
    }
    unsigned kg = 1, kr = 0;
    gbar(sy, bid, kg);

    for (int t = 0; t < TDn; ++t) {
        const int p = t & 1;
        const float* h1r = h1v + p*(Bb*Hh);
        float*       h1w = h1v + (p^1)*(Bb*Hh);
        const float* h0r = h0b + p*(Bb*Hh);
        float*       h0w = h0b + (p^1)*(Bb*Hh);

        // prefetch this step's g0e gates (plain cached loads; written pre-kernel)
        float ge0 = 0.f, ge1 = 0.f, ge2 = 0.f, ge3 = 0.f;
        if (l < 16) {
            const float* gp = g0e + ((size_t)(t*Bb + l))*(4*Hh) + j;
            ge0 = gp[0]; ge1 = gp[Hh]; ge2 = gp[2*Hh]; ge3 = gp[3*Hh];
        }

        // ===== phase Q (j-waves): q[b][j] = h1[b] . W2row_j + b2 =====
        {
            for (int i = tid*4; i < Bb*Hh; i += 2048)
                *(f32x4*)&lds[swz(i)] = gload4(&h1r[i]);
            __syncthreads();
            float qv = 0.f;
            #pragma unroll 4
            for (int b = 0; b < Bb; ++b) {
                f32x4 ha = *(const f32x4*)&lds[swz(b*Hh + k0)];
                f32x4 hd = *(const f32x4*)&lds[swz(b*Hh + k0 + 4)];
                float s = dot4(ha, w2a) + dot4(hd, w2d);
                s = wsum(s);
                qv = (l == b) ? s + w2bias : qv;
            }
            if (l < 16) gstore1(&qb[l*Hh + j], qv);
        }
        gbar(sy, bid, ++kg);

        // ===== phase C (batch group): scores for e in [u4*64, u4*64+64) =====
        {
            if (tid < 128) *(f32x4*)&lds[tid*4] = gload4(&qb[gb*Hh + tid*4]);
            __syncthreads();
            f32x4 qa = *(const f32x4*)&lds[k0];
            f32x4 qd = *(const f32x4*)&lds[k0 + 4];
            float myS = 0.f;
            #pragma unroll
            for (int i = 0; i < 8; ++i) {
                const int e = se0 + i;
                const float* ep = encP + ((size_t)(gb*TEn + e))*Hh + k0;
                f32x4 ea = *(const f32x4*)ep, ed = *(const f32x4*)(ep + 4);
                float s = 0.f;
                #pragma unroll
                for (int c = 0; c < 4; ++c)
                    s += tanhfast(ea[c] + qa[c]) * va[c] + tanhfast(ed[c] + qd[c]) * vd[c];
                s = wsum(s);
                myS = (l == i) ? s : myS;
            }
            if (l < 8)
                gstore1(&sc[gb*TEn + se0 + l], (msk == 0) ? -1e9f : (myS + vbias));
        }
        rbar(sy, gb, u4, ++kr);

        // ===== phase D (batch group): softmax (dup) + ctx cols [u4*128,+128) =====
        {
            f32x4 s4 = gload4(&sc[gb*TEn + (l << 2)]);
            float mx = wmax(fmaxf(fmaxf(s4[0], s4[1]), fmaxf(s4[2], s4[3])));
            f32x4 e4; float sm = 0.f;
            #pragma unroll
            for (int c = 0; c < 4; ++c) { e4[c] = __expf(s4[c] - mx); sm += e4[c]; }
            sm = wsum(sm);
            const float inv = 1.0f / sm;
            float myC = 0.f;
            #pragma unroll 4
            for (int i = 0; i < 16; ++i) {
                const int h = ch0 + i;
                f32x4 en = *(const f32x4*)&encT[((size_t)(gb*Hh + h))*TEn + (l << 2)];
                float s = wsum(dot4(e4, en));
                myC = (l == i) ? s : myC;
            }
            if (l < 16) gstore1(&ctx[gb*Hh + ch0 + l], myC * inv);
        }
        gbar(sy, bid, ++kg);

        // ===== phase L0 (j-waves): LSTM layer 0 =====
        {
            for (int i = tid*4; i < Bb*Hh; i += 2048) {
                *(f32x4*)&lds[swz(i)]          = gload4(&ctx[i]);
                *(f32x4*)&lds[swz(Bb*Hh + i)]  = gload4(&h0r[i]);
            }
            __syncthreads();
            float ls0 = 0.f, ls1 = 0.f, ls2 = 0.f, ls3 = 0.f;
            #pragma unroll 4
            for (int b = 0; b < Bb; ++b) {
                f32x4 xa = *(const f32x4*)&lds[swz(b*Hh + k0)];
                f32x4 xd = *(const f32x4*)&lds[swz(b*Hh + k0 + 4)];
                f32x4 ha = *(const f32x4*)&lds[swz(Bb*Hh + b*Hh + k0)];
                f32x4 hd = *(const f32x4*)&lds[swz(Bb*Hh + b*Hh + k0 + 4)];
                float s0 = dot4(wi0a[0],xa)+dot4(wi0b[0],xd)+dot4(wh0a[0],ha)+dot4(wh0b[0],hd);
                float s1 = dot4(wi0a[1],xa)+dot4(wi0b[1],xd)+dot4(wh0a[1],ha)+dot4(wh0b[1],hd);
                float s2 = dot4(wi0a[2],xa)+dot4(wi0b[2],xd)+dot4(wh0a[2],ha)+dot4(wh0b[2],hd);
                float s3 = dot4(wi0a[3],xa)+dot4(wi0b[3],xd)+dot4(wh0a[3],ha)+dot4(wh0b[3],hd);
                wsum4(s0, s1, s2, s3);
                if (l == b) { ls0 = s0; ls1 = s1; ls2 = s2; ls3 = s3; }
            }
            if (l < 16) {
                float ii = sigm(ls0 + ge0), ff = sigm(ls1 + ge1);
                float gg = tanhfast(ls2 + ge2), oo = sigm(ls3 + ge3);
                float cn = ff*c0r + ii*gg;
                c0r = cn;
                gstore1(&h0w[l*Hh + j], oo * tanhfast(cn));
            }
        }
        gbar(sy, bid, ++kg);

        // ===== phase L1 (j-waves): LSTM layer 1 + bf16 h1 store =====
        {
            for (int i = tid*4; i < Bb*Hh; i += 2048) {
                *(f32x4*)&lds[swz(i)]          = gload4(&h0w[i]);
                *(f32x4*)&lds[swz(Bb*Hh + i)]  = gload4(&h1r[i]);
            }
            __syncthreads();
            float ls0 = 0.f, ls1 = 0.f, ls2 = 0.f, ls3 = 0.f;
            #pragma unroll 4
            for (int b = 0; b < Bb; ++b) {
                f32x4 xa = *(const f32x4*)&lds[swz(b*Hh + k0)];
                f32x4 xd = *(const f32x4*)&lds[swz(b*Hh + k0 + 4)];
                f32x4 ha = *(const f32x4*)&lds[swz(Bb*Hh + b*Hh + k0)];
                f32x4 hd = *(const f32x4*)&lds[swz(Bb*Hh + b*Hh + k0 + 4)];
                float s0 = dot4(wi1a[0],xa)+dot4(wi1b[0],xd)+dot4(wh1a[0],ha)+dot4(wh1b[0],hd);
                float s1 = dot4(wi1a[1],xa)+dot4(wi1b[1],xd)+dot4(wh1a[1],ha)+dot4(wh1b[1],hd);
                float s2 = dot4(wi1a[2],xa)+dot4(wi1b[2],xd)+dot4(wh1a[2],ha)+dot4(wh1b[2],hd);
                float s3 = dot4(wi1a[3],xa)+dot4(wi1b[3],xd)+dot4(wh1a[3],ha)+dot4(wh1b[3],hd);
                wsum4(s0, s1, s2, s3);
                if (l == b) { ls0 = s0; ls1 = s1; ls2 = s2; ls3 = s3; }
            }
            if (l < 16) {
                float ii = sigm(ls0 + bb1[0]), ff = sigm(ls1 + bb1[1]);
                float gg = tanhfast(ls2 + bb1[2]), oo = sigm(ls3 + bb1[3]);
                float cn = ff*c1r + ii*gg;
                c1r = cn;
                float hn = oo * tanhfast(cn);
                gstore1(&h1w[l*Hh + j], hn);
                gstoreu16(&h1bf[((size_t)(t*Bb + l))*Hh + j], f2bf(hn));
            }
        }
        gbar(sy, bid, ++kg);
    }
}

extern "C" void kernel_launch(void* const* d_in, const int* in_sizes, int n_in,
                              void* d_out, int out_size, void* d_ws, size_t ws_size,
                              hipStream_t stream)
{
    const int*   ids  = (const int*)d_in[0];
    const float* ih   = (const float*)d_in[1];
    const float* ic   = (const float*)d_in[2];
    const float* enc  = (const float*)d_in[3];
    const int*   smask= (const int*)d_in[4];
    const float* emb  = (const float*)d_in[5];
    const float* W1w  = (const float*)d_in[6];
    const float* W1b  = (const float*)d_in[7];
    const float* W2w  = (const float*)d_in[8];
    const float* W2b  = (const float*)d_in[9];
    const float* vw   = (const float*)d_in[10];
    const float* vb   = (const float*)d_in[11];
    const float* Wi0  = (const float*)d_in[12];
    const float* Wh0  = (const float*)d_in[13];
    const float* bi0  = (const float*)d_in[14];
    const float* bh0  = (const float*)d_in[15];
    const float* Wi1  = (const float*)d_in[16];
    const float* Wh1  = (const float*)d_in[17];
    const float* bi1  = (const float*)d_in[18];
    const float* bh1  = (const float*)d_in[19];
    const float* fcw  = (const float*)d_in[20];
    const float* fcb  = (const float*)d_in[21];
    float* out = (float*)d_out;
    char*  ws  = (char*)d_ws;

    // flags must start at 0 (ws is poisoned 0xAA before timing)
    hipMemsetAsync(ws + OFF_SYNC, 0, 4096, stream);

    // prep: fc_w -> bf16 (padded)
    prep_fcw_kernel<<<dim3((unsigned)((size_t)NPAD*Hh/8/256)), dim3(256), 0, stream>>>(
        fcw, (unsigned short*)(ws + OFF_FCWB));

    // prep: enc transpose
    transpose_kernel<<<dim3(TEn/32, Hh/32, Bb), dim3(32, 8), 0, stream>>>(
        enc, (float*)(ws + OFF_ENCT));

    // enc_proj = enc @ W1^T + b1
    gemm_bt<0,0,0><<<dim3(Hh/128, (Bb*TEn)/128), dim3(256), 0, stream>>>(
        enc, W1w, W1b, nullptr, (float*)(ws + OFF_ENCP),
        Bb*TEn, Hh, Hh, Hh, nullptr, 0);

    // g0_emb = emb[ids] @ W_ih0[:, :E]^T + b_ih0 + b_hh0
    gemm_bt<0,1,0><<<dim3((4*Hh)/128, (TDn*Bb)/128), dim3(256), 0, stream>>>(
        emb, Wi0, bi0, bh0, (float*)(ws + OFF_G0E),
        TDn*Bb, 4*Hh, Ee, Ee + Hh, ids, 0);

    // sequential recurrence (cooperative, 64 blocks x 512 threads)
    {
        void* args[] = { (void*)&ih, (void*)&ic, (void*)&W2w, (void*)&W2b,
                         (void*)&vw, (void*)&vb, (void*)&smask,
                         (void*)&Wi0, (void*)&Wh0, (void*)&Wi1, (void*)&Wh1,
                         (void*)&bi1, (void*)&bh1, (void*)&ws };
        hipLaunchCooperativeKernel((void*)recur_kernel, dim3(NBLK), dim3(512), args, 0, stream);
    }

    // logits = h1_all @ fc_w^T + fc_b   (batched over all 64 steps)
    gemm_bt<1,0,1><<<dim3(NPAD/128, (TDn*Bb)/128), dim3(256), 0, stream>>>(
        ws + OFF_H1B, ws + OFF_FCWB, fcb, nullptr, out,
        TDn*Bb, NPAD, Hh, Hh, nullptr, Vv);
}

// Round 6
// 3181.072 us; speedup vs baseline: 2.9616x; 1.0571x over previous
//
#include <hip/hip_runtime.h>

#define DI __device__ __forceinline__

typedef __attribute__((ext_vector_type(2))) float f32x2;
typedef __attribute__((ext_vector_type(4))) float f32x4;
typedef __attribute__((ext_vector_type(8))) short bf16x8;
typedef __attribute__((ext_vector_type(8))) unsigned short u16x8;

constexpr int Vv = 50257, NPAD = 50304, Ee = 512, Hh = 512, Bb = 16, TDn = 64, TEn = 256;
constexpr int NBLK = 64;   // recurrence blocks, 512 thr each -> 512 waves

// ---- workspace layout (bytes) ----
constexpr size_t OFF_ENCP = 0;                                          // (B*TE, H) f32
constexpr size_t OFF_ENCT = OFF_ENCP + (size_t)Bb*TEn*Hh*4;             // (B, H, TE) f32
constexpr size_t OFF_G0E  = OFF_ENCT + (size_t)Bb*Hh*TEn*4;             // (TD*B, 4H) f32
constexpr size_t OFF_FCWB = OFF_G0E  + (size_t)TDn*Bb*4*Hh*4;           // (NPAD, H) bf16
constexpr size_t OFF_H1B  = OFF_FCWB + (size_t)NPAD*Hh*2;               // (TD*B, H) bf16
constexpr size_t OFF_Q    = OFF_H1B  + (size_t)TDn*Bb*Hh*2;             // (B, H) f32
constexpr size_t OFF_SC   = OFF_Q    + (size_t)Bb*Hh*4;                 // (B, TE) f32
constexpr size_t OFF_CTX  = OFF_SC   + (size_t)Bb*TEn*4;                // (B, H) f32
constexpr size_t OFF_H0   = OFF_CTX  + (size_t)Bb*Hh*4;                 // 2x (B,H)
constexpr size_t OFF_H1   = OFF_H0   + (size_t)2*Bb*Hh*4;               // 2x (B,H)
constexpr size_t OFF_SYNC = OFF_H1   + (size_t)2*Bb*Hh*4;               // 8 KiB sync area
// sync layout (128B-line granules):
//   arrA @0     : 8 lines (arrival bytes, polled ONLY by detector block 0)
//   arrB @1024
//   genA @2048  : 8 replicated release lines (u32 = kg); block polls gen[bid&7]
//   genB @3072
//   grpA @4096  : 16 group words (u32, byte per u4)
//   grpB @6144

DI float dot4(f32x4 a, f32x4 b) { return a[0]*b[0] + a[1]*b[1] + a[2]*b[2] + a[3]*b[3]; }
DI float wsum(float v) { for (int m = 32; m; m >>= 1) v += __shfl_xor(v, m, 64); return v; }
DI float wmax(float v) { for (int m = 32; m; m >>= 1) v = fmaxf(v, __shfl_xor(v, m, 64)); return v; }
DI void wsum4(float& a, float& b, float& c, float& d) {
    #pragma unroll
    for (int m = 32; m; m >>= 1) {
        a += __shfl_xor(a, m, 64);
        b += __shfl_xor(b, m, 64);
        c += __shfl_xor(c, m, 64);
        d += __shfl_xor(d, m, 64);
    }
}
DI float tanhfast(float x) { float e = __expf(2.f * x); return 1.f - 2.f / (e + 1.f); }
DI float sigm(float x) { return 1.f / (1.f + __expf(-x)); }

// LDS bank-quad spreading swizzle (dword index, preserves 16B blocks)
DI int swz(int a) { return a ^ (((a >> 5) & 7) << 2); }

// ---- agent-scope (device-coherent) data path for cross-block state ----
DI float gload1(const float* p) {
    return __hip_atomic_load(p, __ATOMIC_RELAXED, __HIP_MEMORY_SCOPE_AGENT);
}
DI void gstore1(float* p, float v) {
    __hip_atomic_store(p, v, __ATOMIC_RELAXED, __HIP_MEMORY_SCOPE_AGENT);
}
DI f32x2 gload2(const float* p) {
    unsigned long long u = __hip_atomic_load((const unsigned long long*)p,
                                             __ATOMIC_RELAXED, __HIP_MEMORY_SCOPE_AGENT);
    return __builtin_bit_cast(f32x2, u);
}
DI void gstore2(float* p, f32x2 v) {
    __hip_atomic_store((unsigned long long*)p, __builtin_bit_cast(unsigned long long, v),
                       __ATOMIC_RELAXED, __HIP_MEMORY_SCOPE_AGENT);
}
DI f32x4 gload4(const float* p) {
    f32x2 a = gload2(p), b = gload2(p + 2);
    f32x4 r; r[0] = a[0]; r[1] = a[1]; r[2] = b[0]; r[3] = b[1];
    return r;
}
DI void gstoreu16(unsigned short* p, unsigned short v) {
    __hip_atomic_store(p, v, __ATOMIC_RELAXED, __HIP_MEMORY_SCOPE_AGENT);
}

DI unsigned short f2bf(float f) {
    unsigned u = __builtin_bit_cast(unsigned, f);
    unsigned r = (u + 0x7FFFu + ((u >> 16) & 1u)) >> 16;
    return (unsigned short)r;
}
DI u16x8 cvt8(f32x4 a, f32x4 b) {
    u16x8 r;
    r[0]=f2bf(a[0]); r[1]=f2bf(a[1]); r[2]=f2bf(a[2]); r[3]=f2bf(a[3]);
    r[4]=f2bf(b[0]); r[5]=f2bf(b[1]); r[6]=f2bf(b[2]); r[7]=f2bf(b[3]);
    return r;
}

// ---- detector grid barrier ----
// Arrivals: byte stores to 8 lines read ONLY by block 0's wave 0 (no poll storm
// on written lines). Release: block 0 writes kg to 8 replicated gen lines;
// block bid polls gen[bid&7] (<=8 pollers per line). Parity ping-pong arrays.
DI void gbar(char* sy, int bid, unsigned kg) {
    __syncthreads();
    const size_t pofs = (kg & 1) ? 0 : 1024;
    unsigned long long* arr = (unsigned long long*)(sy + pofs);           // line i: arr + i*16
    unsigned* gen = (unsigned*)(sy + 2048 + pofs);                        // line i: gen + i*32
    const int tid = threadIdx.x;
    if (tid == 0) {
        asm volatile("s_waitcnt vmcnt(0)" ::: "memory");
        char* p = (char*)(arr + (size_t)(bid >> 3) * 16) + (bid & 7);
        __hip_atomic_store(p, (char)(unsigned char)kg, __ATOMIC_RELAXED, __HIP_MEMORY_SCOPE_AGENT);
    }
    if (bid == 0) {
        if (tid < 64) {
            const unsigned long long pat = 0x0101010101010101ULL * (unsigned char)kg;
            for (;;) {
                bool ok = true;
                if (tid < 8)
                    ok = (__hip_atomic_load(arr + (size_t)tid * 16, __ATOMIC_RELAXED,
                                            __HIP_MEMORY_SCOPE_AGENT) == pat);
                if (__all(ok)) break;
                __builtin_amdgcn_s_sleep(2);
            }
            asm volatile("" ::: "memory");
            if (tid < 8)
                __hip_atomic_store(gen + (size_t)tid * 32, kg, __ATOMIC_RELAXED,
                                   __HIP_MEMORY_SCOPE_AGENT);
        }
    } else if (tid == 0) {
        unsigned* gp = gen + (size_t)(bid & 7) * 32;
        while (__hip_atomic_load(gp, __ATOMIC_RELAXED, __HIP_MEMORY_SCOPE_AGENT) != kg)
            __builtin_amdgcn_s_sleep(2);
    }
    __syncthreads();
}

// ---- 4-block group barrier: one u32 word per group (same-XCD blocks) ----
DI void rbar(char* sy, int gb, int u4, unsigned kr) {
    __syncthreads();
    if (threadIdx.x == 0) {
        const size_t pofs = (kr & 1) ? 4096 : 6144;
        unsigned* w = (unsigned*)(sy + pofs) + (size_t)gb * 32;
        asm volatile("s_waitcnt vmcnt(0)" ::: "memory");
        __hip_atomic_store((char*)w + u4, (char)(unsigned char)kr, __ATOMIC_RELAXED,
                           __HIP_MEMORY_SCOPE_AGENT);
        const unsigned pat = 0x01010101u * (unsigned char)kr;
        while (__hip_atomic_load(w, __ATOMIC_RELAXED, __HIP_MEMORY_SCOPE_AGENT) != pat)
            __builtin_amdgcn_s_sleep(2);
    }
    __syncthreads();
}

// ---- prep: fc_w f32 -> bf16, padded to NPAD rows ----
__global__ void prep_fcw_kernel(const float* __restrict__ src, unsigned short* __restrict__ dst) {
    size_t i = ((size_t)blockIdx.x * 256 + threadIdx.x) << 3;
    int n = (int)(i >> 9);
    u16x8 v = {0,0,0,0,0,0,0,0};
    if (n < Vv) {
        const float* p = src + i;
        v = cvt8(*(const f32x4*)p, *(const f32x4*)(p + 4));
    }
    *(u16x8*)(dst + i) = v;
}

// ---- prep: enc (B,TE,H) -> encT (B,H,TE) ----
__global__ void transpose_kernel(const float* __restrict__ enc, float* __restrict__ encT) {
    __shared__ float tile[32][33];
    const int b = blockIdx.z, e0 = blockIdx.x << 5, h0 = blockIdx.y << 5;
    const int tx = threadIdx.x, ty = threadIdx.y;  // 32 x 8
    #pragma unroll
    for (int i = 0; i < 4; ++i)
        tile[ty + i*8][tx] = enc[((size_t)(b*TEn + e0 + ty + i*8))*Hh + h0 + tx];
    __syncthreads();
    #pragma unroll
    for (int i = 0; i < 4; ++i)
        encT[((size_t)(b*Hh + h0 + ty + i*8))*TEn + e0 + tx] = tile[tx][ty + i*8];
}

// ---- MFMA bf16 GEMM: C[m][n] = sum_k A[m][k]*B[n][k] (+bias), 128x128x32 tiles ----
template<int SRCBF, int GATHER, int OUTM>
__global__ __launch_bounds__(256, 2) void gemm_bt(
    const void* __restrict__ Av, const void* __restrict__ Bv,
    const float* __restrict__ bias, const float* __restrict__ bias2,
    float* __restrict__ Cout, int M, int N, int K, int ldb,
    const int* __restrict__ ids, int NV)
{
    __shared__ unsigned short As[128*32], Bs[128*32];
    const int tid = threadIdx.x;
    const int bn = blockIdx.x, bm = blockIdx.y;
    const int w = tid >> 6, l = tid & 63;
    const int wm = w >> 1, wn = w & 1;
    const int lr = l & 15, ls = l >> 4;
    f32x4 acc[4][4] = {};

    const int r0 = tid >> 2, c0 = (tid & 3) << 3;

    for (int kb = 0; kb < K; kb += 32) {
        #pragma unroll
        for (int half = 0; half < 2; ++half) {
            const int rr = r0 + half*64;
            {   // A tile
                const int gm = bm*128 + rr;
                size_t arow = GATHER ? (size_t)ids[((gm & 15) << 6) + (gm >> 4)] : (size_t)gm;
                u16x8 v;
                if (SRCBF) {
                    v = *(const u16x8*)((const unsigned short*)Av + arow*(size_t)K + kb + c0);
                } else {
                    const float* ap = (const float*)Av + arow*(size_t)K + kb + c0;
                    v = cvt8(*(const f32x4*)ap, *(const f32x4*)(ap + 4));
                }
                *(u16x8*)&As[rr*32 + c0] = v;
            }
            {   // B tile
                const size_t brow = (size_t)(bn*128 + rr);
                u16x8 v;
                if (SRCBF) {
                    v = *(const u16x8*)((const unsigned short*)Bv + brow*(size_t)ldb + kb + c0);
                } else {
                    const float* bp = (const float*)Bv + brow*(size_t)ldb + kb + c0;
                    v = cvt8(*(const f32x4*)bp, *(const f32x4*)(bp + 4));
                }
                *(u16x8*)&Bs[rr*32 + c0] = v;
            }
        }
        __syncthreads();
        bf16x8 af[4], bfv[4];
        #pragma unroll
        for (int mt = 0; mt < 4; ++mt) af[mt]  = *(const bf16x8*)&As[(wm*64 + mt*16 + lr)*32 + ls*8];
        #pragma unroll
        for (int nt = 0; nt < 4; ++nt) bfv[nt] = *(const bf16x8*)&Bs[(wn*64 + nt*16 + lr)*32 + ls*8];
        #pragma unroll
        for (int mt = 0; mt < 4; ++mt)
            #pragma unroll
            for (int nt = 0; nt < 4; ++nt)
                acc[mt][nt] = __builtin_amdgcn_mfma_f32_16x16x32_bf16(af[mt], bfv[nt], acc[mt][nt], 0, 0, 0);
        __syncthreads();
    }

    #pragma unroll
    for (int mt = 0; mt < 4; ++mt) {
        #pragma unroll
        for (int nt = 0; nt < 4; ++nt) {
            const int n = bn*128 + wn*64 + nt*16 + lr;
            const int mbase = bm*128 + wm*64 + mt*16 + ls*4;
            f32x4 a = acc[mt][nt];
            #pragma unroll
            for (int r = 0; r < 4; ++r) {
                const int m = mbase + r;
                if (OUTM == 0) {
                    float v = a[r] + bias[n] + (bias2 ? bias2[n] : 0.f);
                    Cout[(size_t)m*N + n] = v;
                } else {
                    if (n < NV) {
                        float v = a[r] + bias[n];
                        Cout[(size_t)(((m & 15) << 6) + (m >> 4))*NV + n] = v;
                    }
                }
            }
        }
    }
}

// ---- cooperative recurrence: 64 blocks x 512 thr ----
// j-phases (Q, LSTM0, LSTM1): wave j = bid*8+wid owns gate-row j, weights in VGPRs.
// batch-phases (scores, softmax+ctx): group gb = bid&15 (4 blocks, SAME XCD since
// they differ by 16 = 0 mod 8); u4 = bid>>4.
// Schedule/step: Q -G- scores -g- softmax+ctx -G- LSTM0 -G- LSTM1 -G-
__global__ __launch_bounds__(512, 1) void recur_kernel(
    const float* __restrict__ ih, const float* __restrict__ ic,
    const float* __restrict__ W2w, const float* __restrict__ W2b,
    const float* __restrict__ vw, const float* __restrict__ vb,
    const int* __restrict__ smask,
    const float* __restrict__ Wi0, const float* __restrict__ Wh0,
    const float* __restrict__ Wi1, const float* __restrict__ Wh1,
    const float* __restrict__ bi1, const float* __restrict__ bh1,
    char* __restrict__ ws)
{
    float* encP = (float*)(ws + OFF_ENCP);
    float* encT = (float*)(ws + OFF_ENCT);
    float* g0e  = (float*)(ws + OFF_G0E);
    unsigned short* h1bf = (unsigned short*)(ws + OFF_H1B);
    float* qb  = (float*)(ws + OFF_Q);
    float* sc  = (float*)(ws + OFF_SC);
    float* ctx = (float*)(ws + OFF_CTX);
    float* h0b = (float*)(ws + OFF_H0);
    float* h1v = (float*)(ws + OFF_H1);
    char* sy   = (char*)(ws + OFF_SYNC);

    __shared__ float lds[2 * Bb * Hh];   // 64 KiB staging

    const int tid = threadIdx.x, bid = blockIdx.x;
    const int wid = tid >> 6, l = tid & 63;
    const int j  = (bid << 3) + wid;     // owned gate-row, 0..511
    const int k0 = l << 3;               // lane k-slice (8 floats)

    // ---- persistent per-lane LSTM weight fragments ----
    f32x4 wi0a[4], wi0b[4], wh0a[4], wh0b[4];
    f32x4 wi1a[4], wi1b[4], wh1a[4], wh1b[4];
    float bb1[4];
    #pragma unroll
    for (int g = 0; g < 4; ++g) {
        const float* p0 = Wi0 + (size_t)(g*Hh + j)*(Ee + Hh) + Ee + k0;
        wi0a[g] = *(const f32x4*)p0; wi0b[g] = *(const f32x4*)(p0 + 4);
        const float* p1 = Wh0 + (size_t)(g*Hh + j)*Hh + k0;
        wh0a[g] = *(const f32x4*)p1; wh0b[g] = *(const f32x4*)(p1 + 4);
        const float* p2 = Wi1 + (size_t)(g*Hh + j)*Hh + k0;
        wi1a[g] = *(const f32x4*)p2; wi1b[g] = *(const f32x4*)(p2 + 4);
        const float* p3 = Wh1 + (size_t)(g*Hh + j)*Hh + k0;
        wh1a[g] = *(const f32x4*)p3; wh1b[g] = *(const f32x4*)(p3 + 4);
        bb1[g] = bi1[g*Hh + j] + bh1[g*Hh + j];
    }
    // t-invariant attention params
    const float* wr = W2w + (size_t)j*Hh + k0;
    const f32x4 w2a = *(const f32x4*)wr, w2d = *(const f32x4*)(wr + 4);
    const float w2bias = W2b[j];
    const f32x4 va = *(const f32x4*)&vw[k0], vd = *(const f32x4*)&vw[k0 + 4];
    const float vbias = vb[0];

    // cell state lives in lane b (b = l < 16)
    float c0r = (l < 16) ? ic[l*Hh + j]           : 0.f;
    float c1r = (l < 16) ? ic[Bb*Hh + l*Hh + j]   : 0.f;

    // batch-phase mapping: group gb = bid&15 (same XCD), sub-index u4 = bid>>4.
    // encP/encT per-XCD footprint: 2 batches x 1 MB = 2 MB < 4 MB L2.
    const int gb  = bid & 15, u4 = bid >> 4;
    const int se0 = u4*64 + wid*8;        // 8 score rows per wave
    const int ch0 = u4*128 + wid*16;      // 16 ctx cols per wave
    const int msk = (l < 8) ? smask[gb*TEn + se0 + l] : 1;

    // init h double-buffers (parity 0)
    for (int i = (bid*512 + tid)*4; i < Bb*Hh; i += NBLK*512*4) {
        gstore2(&h0b[i],     *(const f32x2*)&ih[i]);
        gstore2(&h0b[i + 2], *(const f32x2*)&ih[i + 2]);
        gstore2(&h1v[i],     *(const f32x2*)&ih[Bb*Hh + i]);
        gstore2(&h1v[i + 2], *(const f32x2*)&ih[Bb*Hh + i + 2]);
    }
    unsigned kg = 1, kr = 0;
    gbar(sy, bid, kg);

    for (int t = 0; t < TDn; ++t) {
        const int p = t & 1;
        const float* h1r = h1v + p*(Bb*Hh);
        float*       h1w = h1v + (p^1)*(Bb*Hh);
        const float* h0r = h0b + p*(Bb*Hh);
        float*       h0w = h0b + (p^1)*(Bb*Hh);

        // prefetch this step's g0e gates (plain cached loads; written pre-kernel)
        float ge0 = 0.f, ge1 = 0.f, ge2 = 0.f, ge3 = 0.f;
        if (l < 16) {
            const float* gp = g0e + ((size_t)(t*Bb + l))*(4*Hh) + j;
            ge0 = gp[0]; ge1 = gp[Hh]; ge2 = gp[2*Hh]; ge3 = gp[3*Hh];
        }

        // ===== phase Q (j-waves): q[b][j] = h1[b] . W2row_j + b2 =====
        {
            for (int i = tid*4; i < Bb*Hh; i += 2048)
                *(f32x4*)&lds[swz(i)] = gload4(&h1r[i]);
            __syncthreads();
            float qv = 0.f;
            #pragma unroll 4
            for (int b = 0; b < Bb; ++b) {
                f32x4 ha = *(const f32x4*)&lds[swz(b*Hh + k0)];
                f32x4 hd = *(const f32x4*)&lds[swz(b*Hh + k0 + 4)];
                float s = dot4(ha, w2a) + dot4(hd, w2d);
                s = wsum(s);
                qv = (l == b) ? s + w2bias : qv;
            }
            if (l < 16) gstore1(&qb[l*Hh + j], qv);
        }
        gbar(sy, bid, ++kg);

        // ===== phase C (batch group): scores for e in [u4*64, u4*64+64) =====
        {
            if (tid < 128) *(f32x4*)&lds[tid*4] = gload4(&qb[gb*Hh + tid*4]);
            __syncthreads();
            f32x4 qa = *(const f32x4*)&lds[k0];
            f32x4 qd = *(const f32x4*)&lds[k0 + 4];
            float myS = 0.f;
            #pragma unroll
            for (int i = 0; i < 8; ++i) {
                const int e = se0 + i;
                const float* ep = encP + ((size_t)(gb*TEn + e))*Hh + k0;
                f32x4 ea = *(const f32x4*)ep, ed = *(const f32x4*)(ep + 4);
                float s = 0.f;
                #pragma unroll
                for (int c = 0; c < 4; ++c)
                    s += tanhfast(ea[c] + qa[c]) * va[c] + tanhfast(ed[c] + qd[c]) * vd[c];
                s = wsum(s);
                myS = (l == i) ? s : myS;
            }
            if (l < 8)
                gstore1(&sc[gb*TEn + se0 + l], (msk == 0) ? -1e9f : (myS + vbias));
        }
        rbar(sy, gb, u4, ++kr);

        // ===== phase D (batch group): softmax (dup) + ctx cols [u4*128,+128) =====
        {
            f32x4 s4 = gload4(&sc[gb*TEn + (l << 2)]);
            float mx = wmax(fmaxf(fmaxf(s4[0], s4[1]), fmaxf(s4[2], s4[3])));
            f32x4 e4; float sm = 0.f;
            #pragma unroll
            for (int c = 0; c < 4; ++c) { e4[c] = __expf(s4[c] - mx); sm += e4[c]; }
            sm = wsum(sm);
            const float inv = 1.0f / sm;
            float myC = 0.f;
            #pragma unroll 4
            for (int i = 0; i < 16; ++i) {
                const int h = ch0 + i;
                f32x4 en = *(const f32x4*)&encT[((size_t)(gb*Hh + h))*TEn + (l << 2)];
                float s = wsum(dot4(e4, en));
                myC = (l == i) ? s : myC;
            }
            if (l < 16) gstore1(&ctx[gb*Hh + ch0 + l], myC * inv);
        }
        gbar(sy, bid, ++kg);

        // ===== phase L0 (j-waves): LSTM layer 0 =====
        {
            for (int i = tid*4; i < Bb*Hh; i += 2048) {
                *(f32x4*)&lds[swz(i)]          = gload4(&ctx[i]);
                *(f32x4*)&lds[swz(Bb*Hh + i)]  = gload4(&h0r[i]);
            }
            __syncthreads();
            float ls0 = 0.f, ls1 = 0.f, ls2 = 0.f, ls3 = 0.f;
            #pragma unroll 4
            for (int b = 0; b < Bb; ++b) {
                f32x4 xa = *(const f32x4*)&lds[swz(b*Hh + k0)];
                f32x4 xd = *(const f32x4*)&lds[swz(b*Hh + k0 + 4)];
                f32x4 ha = *(const f32x4*)&lds[swz(Bb*Hh + b*Hh + k0)];
                f32x4 hd = *(const f32x4*)&lds[swz(Bb*Hh + b*Hh + k0 + 4)];
                float s0 = dot4(wi0a[0],xa)+dot4(wi0b[0],xd)+dot4(wh0a[0],ha)+dot4(wh0b[0],hd);
                float s1 = dot4(wi0a[1],xa)+dot4(wi0b[1],xd)+dot4(wh0a[1],ha)+dot4(wh0b[1],hd);
                float s2 = dot4(wi0a[2],xa)+dot4(wi0b[2],xd)+dot4(wh0a[2],ha)+dot4(wh0b[2],hd);
                float s3 = dot4(wi0a[3],xa)+dot4(wi0b[3],xd)+dot4(wh0a[3],ha)+dot4(wh0b[3],hd);
                wsum4(s0, s1, s2, s3);
                if (l == b) { ls0 = s0; ls1 = s1; ls2 = s2; ls3 = s3; }
            }
            if (l < 16) {
                float ii = sigm(ls0 + ge0), ff = sigm(ls1 + ge1);
                float gg = tanhfast(ls2 + ge2), oo = sigm(ls3 + ge3);
                float cn = ff*c0r + ii*gg;
                c0r = cn;
                gstore1(&h0w[l*Hh + j], oo * tanhfast(cn));
            }
        }
        gbar(sy, bid, ++kg);

        // ===== phase L1 (j-waves): LSTM layer 1 + bf16 h1 store =====
        {
            for (int i = tid*4; i < Bb*Hh; i += 2048) {
                *(f32x4*)&lds[swz(i)]          = gload4(&h0w[i]);
                *(f32x4*)&lds[swz(Bb*Hh + i)]  = gload4(&h1r[i]);
            }
            __syncthreads();
            float ls0 = 0.f, ls1 = 0.f, ls2 = 0.f, ls3 = 0.f;
            #pragma unroll 4
            for (int b = 0; b < Bb; ++b) {
                f32x4 xa = *(const f32x4*)&lds[swz(b*Hh + k0)];
                f32x4 xd = *(const f32x4*)&lds[swz(b*Hh + k0 + 4)];
                f32x4 ha = *(const f32x4*)&lds[swz(Bb*Hh + b*Hh + k0)];
                f32x4 hd = *(const f32x4*)&lds[swz(Bb*Hh + b*Hh + k0 + 4)];
                float s0 = dot4(wi1a[0],xa)+dot4(wi1b[0],xd)+dot4(wh1a[0],ha)+dot4(wh1b[0],hd);
                float s1 = dot4(wi1a[1],xa)+dot4(wi1b[1],xd)+dot4(wh1a[1],ha)+dot4(wh1b[1],hd);
                float s2 = dot4(wi1a[2],xa)+dot4(wi1b[2],xd)+dot4(wh1a[2],ha)+dot4(wh1b[2],hd);
                float s3 = dot4(wi1a[3],xa)+dot4(wi1b[3],xd)+dot4(wh1a[3],ha)+dot4(wh1b[3],hd);
                wsum4(s0, s1, s2, s3);
                if (l == b) { ls0 = s0; ls1 = s1; ls2 = s2; ls3 = s3; }
            }
            if (l < 16) {
                float ii = sigm(ls0 + bb1[0]), ff = sigm(ls1 + bb1[1]);
                float gg = tanhfast(ls2 + bb1[2]), oo = sigm(ls3 + bb1[3]);
                float cn = ff*c1r + ii*gg;
                c1r = cn;
                float hn = oo * tanhfast(cn);
                gstore1(&h1w[l*Hh + j], hn);
                gstoreu16(&h1bf[((size_t)(t*Bb + l))*Hh + j], f2bf(hn));
            }
        }
        gbar(sy, bid, ++kg);
    }
}

extern "C" void kernel_launch(void* const* d_in, const int* in_sizes, int n_in,
                              void* d_out, int out_size, void* d_ws, size_t ws_size,
                              hipStream_t stream)
{
    const int*   ids  = (const int*)d_in[0];
    const float* ih   = (const float*)d_in[1];
    const float* ic   = (const float*)d_in[2];
    const float* enc  = (const float*)d_in[3];
    const int*   smask= (const int*)d_in[4];
    const float* emb  = (const float*)d_in[5];
    const float* W1w  = (const float*)d_in[6];
    const float* W1b  = (const float*)d_in[7];
    const float* W2w  = (const float*)d_in[8];
    const float* W2b  = (const float*)d_in[9];
    const float* vw   = (const float*)d_in[10];
    const float* vb   = (const float*)d_in[11];
    const float* Wi0  = (const float*)d_in[12];
    const float* Wh0  = (const float*)d_in[13];
    const float* bi0  = (const float*)d_in[14];
    const float* bh0  = (const float*)d_in[15];
    const float* Wi1  = (const float*)d_in[16];
    const float* Wh1  = (const float*)d_in[17];
    const float* bi1  = (const float*)d_in[18];
    const float* bh1  = (const float*)d_in[19];
    const float* fcw  = (const float*)d_in[20];
    const float* fcb  = (const float*)d_in[21];
    float* out = (float*)d_out;
    char*  ws  = (char*)d_ws;

    // flags must start at 0 (ws is poisoned 0xAA before timing)
    hipMemsetAsync(ws + OFF_SYNC, 0, 8192, stream);

    // prep: fc_w -> bf16 (padded)
    prep_fcw_kernel<<<dim3((unsigned)((size_t)NPAD*Hh/8/256)), dim3(256), 0, stream>>>(
        fcw, (unsigned short*)(ws + OFF_FCWB));

    // prep: enc transpose
    transpose_kernel<<<dim3(TEn/32, Hh/32, Bb), dim3(32, 8), 0, stream>>>(
        enc, (float*)(ws + OFF_ENCT));

    // enc_proj = enc @ W1^T + b1
    gemm_bt<0,0,0><<<dim3(Hh/128, (Bb*TEn)/128), dim3(256), 0, stream>>>(
        enc, W1w, W1b, nullptr, (float*)(ws + OFF_ENCP),
        Bb*TEn, Hh, Hh, Hh, nullptr, 0);

    // g0_emb = emb[ids] @ W_ih0[:, :E]^T + b_ih0 + b_hh0
    gemm_bt<0,1,0><<<dim3((4*Hh)/128, (TDn*Bb)/128), dim3(256), 0, stream>>>(
        emb, Wi0, bi0, bh0, (float*)(ws + OFF_G0E),
        TDn*Bb, 4*Hh, Ee, Ee + Hh, ids, 0);

    // sequential recurrence (cooperative, 64 blocks x 512 threads)
    {
        void* args[] = { (void*)&ih, (void*)&ic, (void*)&W2w, (void*)&W2b,
                         (void*)&vw, (void*)&vb, (void*)&smask,
                         (void*)&Wi0, (void*)&Wh0, (void*)&Wi1, (void*)&Wh1,
                         (void*)&bi1, (void*)&bh1, (void*)&ws };
        hipLaunchCooperativeKernel((void*)recur_kernel, dim3(NBLK), dim3(512), args, 0, stream);
    }

    // logits = h1_all @ fc_w^T + fc_b   (batched over all 64 steps)
    gemm_bt<1,0,1><<<dim3(NPAD/128, (TDn*Bb)/128), dim3(256), 0, stream>>>(
        ws + OFF_H1B, ws + OFF_FCWB, fcb, nullptr, out,
        TDn*Bb, NPAD, Hh, Hh, nullptr, Vv);
}